// Round 4
// baseline (11046.113 us; speedup 1.0000x reference)
//
#include <hip/hip_runtime.h>
#include <hip/hip_bf16.h>

// Problem constants
#define Lc 256
#define Bc 64
#define Dc 1024
#define Hc 512
#define Rc 8
#define Cc 6
#define WINc 10
#define NWc 21            // 2*WIN+1
#define Nc (Bc*Lc)        // 16384
#define DHc (Dc+Hc)       // 1536

typedef __hip_bfloat16 bf;

// Runtime-dtype load: isbf==true -> treat p as bf16 array, else fp32 array.
__device__ inline float loadv(const void* p, long i, bool isbf) {
    return isbf ? __bfloat162float(((const bf*)p)[i]) : ((const float*)p)[i];
}

// node id n = b*256+s  ->  feats row s*64+b
__device__ inline long remap_row(int node) { return (long)(((node & 255) << 6) + (node >> 8)); }

// ---------------- dtype probe ----------------
// Little-endian: if the buffer is really fp32, EVEN bf16 elements are the low
// mantissa halves -> random exponents -> huge/NaN values with p~0.45 each.
// Genuine bf16 N(0,1) data never exceeds 1e4.
__global__ void probe_dtype(const void* __restrict__ feats, int* __restrict__ flag)
{
    if (blockIdx.x == 0 && threadIdx.x == 0) {
        const bf* p = (const bf*)feats;
        int bad = 0;
        for (int i = 0; i < 16384; i += 2) {        // even indices only
            float v = __bfloat162float(p[i]);
            if (!(v > -1e4f && v < 1e4f)) bad++;    // catches NaN/Inf/huge
        }
        *flag = (bad == 0) ? 1 : 0;                 // 1 = inputs are bf16
    }
}

// ---------------- Generic tiled GEMM: C[M,N] = act(A@B (+bias) (+C_old)) ----------------
// AMODE: 0 = plain row-major A[m][k]
//        1 = A row m is feats row remap(m + m_off)   (node-major x view)
//        2 = A row m is em row of node (m + m_off): cols 0..1023 feats, 1024..1535 h2buf
// BMODE: 0 = plain row-major B[k][n]
//        1 = transposed: B[n][k]
//        2 = em view, B[k][n] = em[node = n_off + z*256 + k][n]
//        3 = em view transposed, B[n][k] = em[node = n_off + z*256 + n][k]
// A_IN/B_IN: operand is a harness input (dtype = probed flag); otherwise fp32 ws array.
// bias is always a harness input. C is fp32. Batched over blockIdx.z, strides sA/sB/sC.
template<int AMODE, int BMODE, bool A_IN, bool B_IN, int ACT, bool ACCUM, bool BIAS>
__global__ __launch_bounds__(256) void gemm_f32(
    const void* __restrict__ A, const void* __restrict__ B, float* __restrict__ Cm,
    const void* __restrict__ bias,
    const void* __restrict__ feats, const float* __restrict__ h2buf,
    const int* __restrict__ flagp,
    int M, int N, int K, int lda, int ldb, int ldc,
    long sA, long sB, long sC, int m_off, int n_off)
{
    const bool isbf = (*flagp != 0);
    __shared__ float As[16][65];
    __shared__ float Bs[16][65];
    int z = blockIdx.z;
    float* Cb = Cm + z * sC;
    int m0 = blockIdx.y * 64;
    int n0 = blockIdx.x * 64;
    int tid = threadIdx.x;
    int tx = tid & 15, ty = tid >> 4;
    float acc[4][4] = {};
    for (int k0 = 0; k0 < K; k0 += 16) {
        #pragma unroll
        for (int i = 0; i < 4; i++) {
            int idx = tid + i * 256;
            int r = idx >> 4;          // m within tile
            int kk = idx & 15;
            int col = k0 + kk;
            float v;
            if (AMODE == 0) {
                v = loadv(A, z * sA + (long)(m0 + r) * lda + col, A_IN && isbf);
            } else if (AMODE == 1) {
                int node = m0 + r + m_off;
                v = loadv(feats, remap_row(node) * Dc + col, isbf);
            } else {
                int node = m0 + r + m_off;
                v = (col < Dc) ? loadv(feats, remap_row(node) * Dc + col, isbf)
                               : h2buf[(long)node * Hc + (col - Dc)];
            }
            As[kk][r] = v;
        }
        #pragma unroll
        for (int i = 0; i < 4; i++) {
            int idx = tid + i * 256;
            if (BMODE == 0) {
                int kk = idx >> 6, c = idx & 63;
                Bs[kk][c] = loadv(B, z * sB + (long)(k0 + kk) * ldb + (n0 + c), B_IN && isbf);
            } else if (BMODE == 1) {
                int c = idx >> 4, kk = idx & 15;
                Bs[kk][c] = loadv(B, z * sB + (long)(n0 + c) * ldb + (k0 + kk), B_IN && isbf);
            } else if (BMODE == 2) {
                int kk = idx >> 6, c = idx & 63;
                int node = n_off + z * Lc + (k0 + kk);
                int col = n0 + c;
                Bs[kk][c] = (col < Dc) ? loadv(feats, remap_row(node) * Dc + col, isbf)
                                       : h2buf[(long)node * Hc + (col - Dc)];
            } else {
                int c = idx >> 4, kk = idx & 15;
                int node = n_off + z * Lc + (n0 + c);
                int col = k0 + kk;
                Bs[kk][c] = (col < Dc) ? loadv(feats, remap_row(node) * Dc + col, isbf)
                                       : h2buf[(long)node * Hc + (col - Dc)];
            }
        }
        __syncthreads();
        #pragma unroll
        for (int kk = 0; kk < 16; kk++) {
            float a0[4], b0[4];
            #pragma unroll
            for (int i = 0; i < 4; i++) a0[i] = As[kk][ty * 4 + i];
            #pragma unroll
            for (int j = 0; j < 4; j++) b0[j] = Bs[kk][tx * 4 + j];
            #pragma unroll
            for (int i = 0; i < 4; i++)
                #pragma unroll
                for (int j = 0; j < 4; j++)
                    acc[i][j] += a0[i] * b0[j];
        }
        __syncthreads();
    }
    #pragma unroll
    for (int i = 0; i < 4; i++) {
        int m = m0 + ty * 4 + i;
        #pragma unroll
        for (int j = 0; j < 4; j++) {
            int n = n0 + tx * 4 + j;
            float v = acc[i][j];
            if (BIAS) v += loadv(bias, n, isbf);
            if (ACCUM) v += Cb[(long)m * ldc + n];
            if (ACT == 1) v = fmaxf(v, 0.f);
            Cb[(long)m * ldc + n] = v;
        }
    }
}

// ---------------- edge_norm: windowed softmax of scale over source index k ----------------
// scale layout: [(k*64 + b)*256 + j]; enorm: [(b*256 + j)*21 + (k - j + 10)]
__global__ __launch_bounds__(256) void edge_norm_kernel(const float* __restrict__ scale,
                                                        float* __restrict__ enorm)
{
    int g = blockIdx.x * 256 + threadIdx.x;   // b*L + j
    if (g >= Bc * Lc) return;
    int b = g >> 8, j = g & 255;
    int klo = max(0, j - WINc), khi = min(Lc - 1, j + WINc);
    float vals[NWc];
    float m = -1e30f;
    for (int k = klo; k <= khi; k++) {
        float v = scale[((long)k * Bc + b) * Lc + j];
        vals[k - klo] = v;
        m = fmaxf(m, v);
    }
    float s = 0.f;
    for (int k = klo; k <= khi; k++) {
        float e = expf(vals[k - klo] - m);
        vals[k - klo] = e;
        s += e;
    }
    float inv = 1.f / s;
    for (int k = klo; k <= khi; k++)
        enorm[(long)g * NWc + (k - j + WINc)] = vals[k - klo] * inv;
}

// ---------------- RGCN aggregation at dst ----------------
__global__ __launch_bounds__(256) void rgcn_gather(const float* __restrict__ hall,
                                                   const float* __restrict__ enorm,
                                                   const int* __restrict__ speakers,
                                                   float* __restrict__ h1, int chunk_base)
{
    int nloc = blockIdx.x;
    int n = chunk_base + nloc;
    int b = n >> 8, k = n & 255;
    int tid = threadIdx.x;
    int spk = speakers[k * Bc + b];
    int jlo = max(0, k - WINc), jhi = min(Lc - 1, k + WINc);
    float a0 = 0.f, a1 = 0.f;
    for (int j = jlo; j <= jhi; j++) {
        int spj = speakers[j * Bc + b];
        int rel = spj * 4 + spk * 2 + ((j < k) ? 0 : 1);
        float w = enorm[((long)(b * Lc + j)) * NWc + (k - j + WINc)];
        const float* src = hall + ((long)(nloc - k + j)) * (Rc * Hc) + rel * Hc;
        a0 += w * src[tid];
        a1 += w * src[tid + 256];
    }
    h1[(long)n * Hc + tid] = a0;
    h1[(long)n * Hc + tid + 256] = a1;
}

// ---------------- GraphConv neighbor sum ----------------
__global__ __launch_bounds__(256) void nbr_gather(const float* __restrict__ h1,
                                                  float* __restrict__ nbr)
{
    int n = blockIdx.x;
    int b = n >> 8, k = n & 255;
    int tid = threadIdx.x;
    int jlo = max(0, k - WINc), jhi = min(Lc - 1, k + WINc);
    float a0 = 0.f, a1 = 0.f;
    for (int j = jlo; j <= jhi; j++) {
        const float* src = h1 + ((long)(b * Lc + j)) * Hc;
        a0 += src[tid];
        a1 += src[tid + 256];
    }
    nbr[(long)n * Hc + tid] = a0;
    nbr[(long)n * Hc + tid + 256] = a1;
}

// ---------------- tanh + row softmax (rows of length 256) ----------------
__global__ __launch_bounds__(256) void tanh_softmax_rows(float* __restrict__ S)
{
    int row = blockIdx.x;
    int tid = threadIdx.x;
    __shared__ float red[256];
    float v = tanhf(S[(long)row * Lc + tid]);
    red[tid] = v; __syncthreads();
    for (int s = 128; s > 0; s >>= 1) { if (tid < s) red[tid] = fmaxf(red[tid], red[tid + s]); __syncthreads(); }
    float m = red[0]; __syncthreads();
    float e = expf(v - m);
    red[tid] = e; __syncthreads();
    for (int s = 128; s > 0; s >>= 1) { if (tid < s) red[tid] += red[tid + s]; __syncthreads(); }
    float sum = red[0];
    S[(long)row * Lc + tid] = e / sum;
}

// ---------------- final classifier + log_softmax ----------------
__global__ __launch_bounds__(256) void out_kernel(const float* __restrict__ hidden,
                                                  const void* __restrict__ Wfc,
                                                  const void* __restrict__ bfc,
                                                  void* __restrict__ out,
                                                  const int* __restrict__ flagp)
{
    const bool isbf = (*flagp != 0);
    int tid = threadIdx.x;
    int lane = tid & 63;
    int row = blockIdx.x * 4 + (tid >> 6);
    float acc[Cc] = {};
    const float* h = hidden + (long)row * Hc;
    for (int k = lane; k < Hc; k += 64) {
        float hv = h[k];
        #pragma unroll
        for (int c = 0; c < Cc; c++) acc[c] += hv * loadv(Wfc, (long)k * Cc + c, isbf);
    }
    #pragma unroll
    for (int c = 0; c < Cc; c++)
        for (int off = 32; off > 0; off >>= 1) acc[c] += __shfl_down(acc[c], off, 64);
    if (lane == 0) {
        float m = -1e30f;
        #pragma unroll
        for (int c = 0; c < Cc; c++) { acc[c] += loadv(bfc, c, isbf); m = fmaxf(m, acc[c]); }
        float s = 0.f;
        #pragma unroll
        for (int c = 0; c < Cc; c++) s += expf(acc[c] - m);
        float lse = logf(s);
        #pragma unroll
        for (int c = 0; c < Cc; c++) {
            float v = acc[c] - m - lse;
            if (isbf) ((bf*)out)[(long)row * Cc + c] = __float2bfloat16(v);
            else      ((float*)out)[(long)row * Cc + c] = v;
        }
    }
}

extern "C" void kernel_launch(void* const* d_in, const int* in_sizes, int n_in,
                              void* d_out, int out_size, void* d_ws, size_t ws_size,
                              hipStream_t stream)
{
    const void* feats   = d_in[0];   // [L,B,D]
    const void* Wscalar = d_in[1];   // [D,L]
    const void* W_rel   = d_in[2];   // [R,D,H]
    const void* W_root  = d_in[3];   // [D,H]
    const void* b_rgcn  = d_in[4];   // [H]
    const void* W_nbr   = d_in[5];   // [H,H]
    const void* W_self  = d_in[6];   // [H,H]
    const void* b_gc    = d_in[7];   // [H]
    const void* W_match = d_in[8];   // [DH,DH]
    const void* b_match = d_in[9];   // [DH]
    const void* W_lin   = d_in[10];  // [DH,H]
    const void* b_lin   = d_in[11];  // [H]
    const void* W_fc    = d_in[12];  // [H,C]
    const void* b_fc    = d_in[13];  // [C]
    const int* spk      = (const int*)d_in[14]; // [L,B]
    // d_in[15]/d_in[16] = pair_i/pair_k (static banded pattern, recomputed analytically)

    float* ws = (float*)d_ws;
    // Region plan (floats), total 28,655,617 f ~= 109.3 MiB:
    float* R1    = ws;                  // 8,388,608 f : scale[4.19M] -> h1[full] -> S[4.19M]
    float* R2    = ws + 8388608;        // 8,388,608 f : hall chunk -> nbr -> hidden
    float* R3    = ws + 16777216;       // 8,388,608 f : h2
    float* enorm = ws + 25165824;       //   344,064 f
    float* xtc   = ws + 25509888;       // 3,145,728 f : per-chunk xt / att [2048 x 1536]
    int*   flag  = (int*)(ws + 28655616);

    // 0. dtype probe (runs every launch — graph-safe, same work each call)
    probe_dtype<<<dim3(1), 64, 0, stream>>>(feats, flag);

    // 1. scale = feats_flat[16384,1024] @ Wscalar[1024,256]   (row = s*64+b)
    gemm_f32<0, 0, true, true, 0, false, false><<<dim3(4, 256, 1), 256, 0, stream>>>(
        feats, Wscalar, R1, nullptr, feats, nullptr, flag,
        Nc, Lc, Dc, Dc, Lc, Lc, 0, 0, 0, 0, 0);

    // 2. windowed softmax -> edge norms
    edge_norm_kernel<<<dim3(64), 256, 0, stream>>>(R1, enorm);

    // 3. RGCN per 8-conversation chunk: hall = x_chunk @ W_rel[r] (z over r), gather -> h1
    for (int c = 0; c < 8; c++) {
        gemm_f32<1, 0, false, true, 0, false, false><<<dim3(8, 32, 8), 256, 0, stream>>>(
            feats, W_rel, R2, nullptr, feats, nullptr, flag,
            2048, Hc, Dc, Dc, Hc, Rc * Hc,
            0L, (long)Dc * Hc, (long)Hc, c * 2048, 0);
        rgcn_gather<<<dim3(2048), 256, 0, stream>>>(R2, enorm, spk, R1, c * 2048);
    }

    // 4. h1 += x @ W_root + b_rgcn
    gemm_f32<1, 0, false, true, 0, true, true><<<dim3(8, 256, 1), 256, 0, stream>>>(
        feats, W_root, R1, b_rgcn, feats, nullptr, flag,
        Nc, Hc, Dc, Dc, Hc, Hc, 0, 0, 0, 0, 0);

    // 5. GraphConv: nbr = window-sum(h1); h2 = nbr@W_nbr + h1@W_self + b_gc
    nbr_gather<<<dim3(Nc), 256, 0, stream>>>(R1, R2);
    gemm_f32<0, 0, false, true, 0, false, false><<<dim3(8, 256, 1), 256, 0, stream>>>(
        R2, W_nbr, R3, nullptr, feats, nullptr, flag,
        Nc, Hc, Hc, Hc, Hc, Hc, 0, 0, 0, 0, 0);
    gemm_f32<0, 0, false, true, 0, true, true><<<dim3(8, 256, 1), 256, 0, stream>>>(
        R1, W_self, R3, b_gc, feats, nullptr, flag,
        Nc, Hc, Hc, Hc, Hc, Hc, 0, 0, 0, 0, 0);

    // 6. Phase A per chunk: xt = em @ W_match + b_match;  S = xt @ em^T
    for (int c = 0; c < 8; c++) {
        gemm_f32<2, 0, false, true, 0, false, true><<<dim3(24, 32, 1), 256, 0, stream>>>(
            nullptr, W_match, xtc, b_match, feats, R3, flag,
            2048, DHc, DHc, 0, DHc, DHc, 0, 0, 0, c * 2048, 0);
        gemm_f32<0, 3, false, false, 0, false, false><<<dim3(4, 4, 8), 256, 0, stream>>>(
            xtc, nullptr, R1 + (long)c * 524288, nullptr, feats, R3, flag,
            Lc, Lc, DHc, DHc, 0, Lc,
            (long)Lc * DHc, 0, (long)Lc * Lc, 0, c * 2048);
    }

    // 7. softmax(tanh(S)) over s
    tanh_softmax_rows<<<dim3(Nc), 256, 0, stream>>>(R1);

    // 8. Phase B per chunk: att = S @ em;  hidden = relu(att @ W_lin + b_lin)
    for (int c = 0; c < 8; c++) {
        gemm_f32<0, 2, false, false, 0, false, false><<<dim3(24, 4, 8), 256, 0, stream>>>(
            R1 + (long)c * 524288, nullptr, xtc, nullptr, feats, R3, flag,
            Lc, DHc, Lc, Lc, 0, DHc,
            (long)Lc * Lc, 0, (long)Lc * DHc, 0, c * 2048);
        gemm_f32<0, 0, false, true, 1, false, true><<<dim3(8, 32, 1), 256, 0, stream>>>(
            xtc, W_lin, R2 + (long)c * 1048576, b_lin, feats, nullptr, flag,
            2048, Hc, DHc, DHc, Hc, Hc, 0, 0, 0, 0, 0);
    }

    // 9. logits + log_softmax -> out
    out_kernel<<<dim3(Nc / 4), 256, 0, stream>>>(R2, W_fc, b_fc, d_out, flag);
}

// Round 5
// 2332.842 us; speedup vs baseline: 4.7350x; 4.7350x over previous
//
#include <hip/hip_runtime.h>
#include <hip/hip_bf16.h>

// Problem constants
#define Lc 256
#define Bc 64
#define Dc 1024
#define Hc 512
#define Rc 8
#define Cc 6
#define WINc 10
#define NWc 21
#define Nc (Bc*Lc)        // 16384
#define DHc (Dc+Hc)       // 1536

typedef __attribute__((ext_vector_type(8))) short short8;
typedef __attribute__((ext_vector_type(4))) float floatx4;

__device__ inline unsigned short f2b(float x) {
    __hip_bfloat16 h = __float2bfloat16(x);
    return *reinterpret_cast<unsigned short*>(&h);
}
__device__ inline float bf2f(unsigned short u) {
    __hip_bfloat16 h;
    *reinterpret_cast<unsigned short*>(&h) = u;
    return __bfloat162float(h);
}

// node id n = b*256+s  ->  feats row s*64+b
__device__ inline long remap_row(int node) { return (long)(((node & 255) << 6) + (node >> 8)); }

// ---------------- weight transpose fp32 [K][N] -> bf16 [N][K] (ldo) ----------------
__global__ __launch_bounds__(256) void transpose_w(const float* __restrict__ in,
        unsigned short* __restrict__ out, int N, int ldo, long s_in, long s_out)
{
    __shared__ float t[32][33];
    int z = blockIdx.z;
    int n0 = blockIdx.x * 32, k0 = blockIdx.y * 32;
    int tx = threadIdx.x & 31, ty = threadIdx.x >> 5;
    const float* ip = in + z * s_in;
    unsigned short* op = out + z * s_out;
    #pragma unroll
    for (int i = 0; i < 4; i++) t[ty + i * 8][tx] = ip[(long)(k0 + ty + i * 8) * N + n0 + tx];
    __syncthreads();
    #pragma unroll
    for (int i = 0; i < 4; i++) op[(long)(n0 + ty + i * 8) * ldo + k0 + tx] = f2b(t[tx][ty + i * 8]);
}

// ---------------- MFMA GEMM: C[M,N] = act(A@B (+bias) (+C)) ----------------
// AMODE 0: A fp32 rows m0+r            AMODE 1: A fp32 rows remap(m+m_off)
// AMODE 2: A bf16 rows m0+r
// BMODE 0: BT bf16 [n][k] rows         BMODE 1: B bf16 normal [k][n] (LDS transpose)
// CBF: write bf16, else fp32. Tile 128x128, BK=32, 256 thr = 4 waves (64x64 each).
template<int AMODE, int BMODE, bool CBF, bool ACCUM, bool BIAS, bool RELU>
__global__ __launch_bounds__(256) void gemm_mfma(
    const void* __restrict__ Av, const void* __restrict__ Bv, void* __restrict__ Cv,
    const float* __restrict__ bias,
    int K, int lda, int ldb, int ldc,
    long sA, long sB, long sC, int m_off)
{
    __shared__ __align__(16) unsigned short As[128 * 40];
    __shared__ __align__(16) unsigned short Bs[128 * 40];
    const int tid = threadIdx.x;
    const int z = blockIdx.z;
    const int m0 = blockIdx.y * 128;
    const int n0 = blockIdx.x * 128;
    const int lane = tid & 63;
    const int wave = tid >> 6;
    const int wrow = (wave >> 1) * 64;
    const int wcol = (wave & 1) * 64;
    const int q = lane >> 4;
    const int mr = lane & 15;

    floatx4 acc[4][4];
    #pragma unroll
    for (int mt = 0; mt < 4; mt++)
        #pragma unroll
        for (int nt = 0; nt < 4; nt++) acc[mt][nt] = (floatx4){0.f, 0.f, 0.f, 0.f};

    const int r = tid & 127, hh = tid >> 7;        // A / BT staging map
    const int kk = tid >> 3, cg = (tid & 7) * 16;  // B-normal staging map

    long abase;
    if (AMODE == 1) abase = remap_row(m0 + r + m_off) * (long)lda;
    else            abase = (long)(m0 + r) * lda;

    for (int k0 = 0; k0 < K; k0 += 32) {
        // ---- stage A tile (128 x 32)
        if (AMODE <= 1) {
            const float* ap = (const float*)Av + z * sA + abase + k0 + hh * 16;
            float4 f0 = ((const float4*)ap)[0];
            float4 f1 = ((const float4*)ap)[1];
            float4 f2 = ((const float4*)ap)[2];
            float4 f3 = ((const float4*)ap)[3];
            __align__(16) unsigned short tmp[16];
            tmp[0]=f2b(f0.x); tmp[1]=f2b(f0.y); tmp[2]=f2b(f0.z); tmp[3]=f2b(f0.w);
            tmp[4]=f2b(f1.x); tmp[5]=f2b(f1.y); tmp[6]=f2b(f1.z); tmp[7]=f2b(f1.w);
            tmp[8]=f2b(f2.x); tmp[9]=f2b(f2.y); tmp[10]=f2b(f2.z); tmp[11]=f2b(f2.w);
            tmp[12]=f2b(f3.x); tmp[13]=f2b(f3.y); tmp[14]=f2b(f3.z); tmp[15]=f2b(f3.w);
            *(short8*)&As[r * 40 + hh * 16]     = *(short8*)&tmp[0];
            *(short8*)&As[r * 40 + hh * 16 + 8] = *(short8*)&tmp[8];
        } else {
            const unsigned short* ap = (const unsigned short*)Av + z * sA + abase + k0 + hh * 16;
            *(short8*)&As[r * 40 + hh * 16]     = ((const short8*)ap)[0];
            *(short8*)&As[r * 40 + hh * 16 + 8] = ((const short8*)ap)[1];
        }
        // ---- stage B tile (32 x 128) as [n][k]
        if (BMODE == 0) {
            const unsigned short* bp = (const unsigned short*)Bv + z * sB + (long)(n0 + r) * ldb + k0 + hh * 16;
            *(short8*)&Bs[r * 40 + hh * 16]     = ((const short8*)bp)[0];
            *(short8*)&Bs[r * 40 + hh * 16 + 8] = ((const short8*)bp)[1];
        } else {
            const unsigned short* bp = (const unsigned short*)Bv + z * sB + (long)(k0 + kk) * ldb + n0 + cg;
            short8 w0 = ((const short8*)bp)[0];
            short8 w1 = ((const short8*)bp)[1];
            #pragma unroll
            for (int i = 0; i < 8; i++) Bs[(cg + i) * 40 + kk] = (unsigned short)w0[i];
            #pragma unroll
            for (int i = 0; i < 8; i++) Bs[(cg + 8 + i) * 40 + kk] = (unsigned short)w1[i];
        }
        __syncthreads();
        short8 af[4], bfv[4];
        #pragma unroll
        for (int mt = 0; mt < 4; mt++) af[mt]  = *(const short8*)&As[(wrow + mt * 16 + mr) * 40 + q * 8];
        #pragma unroll
        for (int nt = 0; nt < 4; nt++) bfv[nt] = *(const short8*)&Bs[(wcol + nt * 16 + mr) * 40 + q * 8];
        #pragma unroll
        for (int mt = 0; mt < 4; mt++)
            #pragma unroll
            for (int nt = 0; nt < 4; nt++)
                acc[mt][nt] = __builtin_amdgcn_mfma_f32_16x16x32_bf16(af[mt], bfv[nt], acc[mt][nt], 0, 0, 0);
        __syncthreads();
    }

    float* Cf = (float*)Cv;
    unsigned short* Cb = (unsigned short*)Cv;
    #pragma unroll
    for (int mt = 0; mt < 4; mt++) {
        #pragma unroll
        for (int nt = 0; nt < 4; nt++) {
            int col = n0 + wcol + nt * 16 + mr;
            float bv = BIAS ? bias[col] : 0.f;
            #pragma unroll
            for (int rg = 0; rg < 4; rg++) {
                int row = m0 + wrow + mt * 16 + q * 4 + rg;
                long ci = z * sC + (long)row * ldc + col;
                float v = acc[mt][nt][rg] + bv;
                if (ACCUM) v += Cf[ci];
                if (RELU) v = fmaxf(v, 0.f);
                if (CBF) Cb[ci] = f2b(v);
                else     Cf[ci] = v;
            }
        }
    }
}

// ---------------- edge_norm: windowed softmax over k ----------------
__global__ __launch_bounds__(256) void edge_norm_kernel(const float* __restrict__ scale,
                                                        float* __restrict__ enorm)
{
    int g = blockIdx.x * 256 + threadIdx.x;   // b*L + j
    int b = g >> 8, j = g & 255;
    int klo = max(0, j - WINc), khi = min(Lc - 1, j + WINc);
    float vals[NWc];
    float m = -1e30f;
    for (int k = klo; k <= khi; k++) {
        float v = scale[((long)k * Bc + b) * Lc + j];
        vals[k - klo] = v;
        m = fmaxf(m, v);
    }
    float s = 0.f;
    for (int k = klo; k <= khi; k++) {
        float e = expf(vals[k - klo] - m);
        vals[k - klo] = e;
        s += e;
    }
    float inv = 1.f / s;
    for (int k = klo; k <= khi; k++)
        enorm[(long)g * NWc + (k - j + WINc)] = vals[k - klo] * inv;
}

// ---------------- RGCN aggregation (hall is bf16 chunk-local [2048][4096]) ----------------
__global__ __launch_bounds__(256) void rgcn_gather(const unsigned short* __restrict__ hall,
        const float* __restrict__ enorm, const int* __restrict__ speakers,
        float* __restrict__ h1, int chunk_base)
{
    int nloc = blockIdx.x;
    int n = chunk_base + nloc;
    int b = n >> 8, k = n & 255;
    int tid = threadIdx.x;
    int spk = speakers[k * Bc + b];
    int jlo = max(0, k - WINc), jhi = min(Lc - 1, k + WINc);
    float a0 = 0.f, a1 = 0.f;
    for (int j = jlo; j <= jhi; j++) {
        int spj = speakers[j * Bc + b];
        int rel = spj * 4 + spk * 2 + ((j < k) ? 0 : 1);
        float w = enorm[((long)((b << 8) + j)) * NWc + (k - j + WINc)];
        const unsigned short* src = hall + ((long)(nloc - k + j)) * (Rc * Hc) + rel * Hc;
        a0 += w * bf2f(src[tid]);
        a1 += w * bf2f(src[tid + 256]);
    }
    h1[(long)n * Hc + tid] = a0;
    h1[(long)n * Hc + tid + 256] = a1;
}

// ---------------- anh1 = bf16[ concat(window-sum(h1), h1) ]  [N][1024] ----------------
__global__ __launch_bounds__(256) void build_anh1(const float* __restrict__ h1,
                                                  unsigned short* __restrict__ anh1)
{
    int n = blockIdx.x;
    int b = n >> 8, k = n & 255;
    int tid = threadIdx.x;
    int jlo = max(0, k - WINc), jhi = min(Lc - 1, k + WINc);
    float a0 = 0.f, a1 = 0.f;
    for (int j = jlo; j <= jhi; j++) {
        const float* src = h1 + ((long)((b << 8) + j)) * Hc;
        a0 += src[tid];
        a1 += src[tid + 256];
    }
    unsigned short* dst = anh1 + (long)n * 1024;
    const float* self = h1 + (long)n * Hc;
    dst[tid]       = f2b(a0);
    dst[tid + 256] = f2b(a1);
    dst[tid + 512] = f2b(self[tid]);
    dst[tid + 768] = f2b(self[tid + 256]);
}

// ---------------- emc chunk build: [2048][1536] bf16 = concat(x, h2) ----------------
__global__ __launch_bounds__(256) void build_emc(const float* __restrict__ feats,
        const unsigned short* __restrict__ h2bf, unsigned short* __restrict__ emc, int base)
{
    int nloc = blockIdx.x;
    int node = base + nloc;
    int tid = threadIdx.x;
    const float* f = feats + remap_row(node) * Dc;
    unsigned short* e = emc + (long)nloc * DHc;
    float4 v = ((const float4*)f)[tid];
    e[tid * 4 + 0] = f2b(v.x);
    e[tid * 4 + 1] = f2b(v.y);
    e[tid * 4 + 2] = f2b(v.z);
    e[tid * 4 + 3] = f2b(v.w);
    const unsigned short* h = h2bf + (long)node * Hc;
    e[Dc + tid] = h[tid];
    e[Dc + 256 + tid] = h[tid + 256];
}

// ---------------- tanh + row softmax -> bf16 attention weights ----------------
__global__ __launch_bounds__(256) void tanh_softmax_rows(const float* __restrict__ S,
                                                         unsigned short* __restrict__ a)
{
    int row = blockIdx.x;
    int tid = threadIdx.x;
    __shared__ float red[256];
    float v = tanhf(S[(long)row * Lc + tid]);
    red[tid] = v; __syncthreads();
    for (int s = 128; s > 0; s >>= 1) { if (tid < s) red[tid] = fmaxf(red[tid], red[tid + s]); __syncthreads(); }
    float m = red[0]; __syncthreads();
    float e = expf(v - m);
    red[tid] = e; __syncthreads();
    for (int s = 128; s > 0; s >>= 1) { if (tid < s) red[tid] += red[tid + s]; __syncthreads(); }
    float sum = red[0];
    a[(long)row * Lc + tid] = f2b(e / sum);
}

// ---------------- final classifier + log_softmax (fp32 out) ----------------
__global__ __launch_bounds__(256) void out_kernel(const float* __restrict__ hidden,
        const float* __restrict__ Wfc, const float* __restrict__ bfc, float* __restrict__ out)
{
    int tid = threadIdx.x;
    int lane = tid & 63;
    int row = blockIdx.x * 4 + (tid >> 6);
    float acc[Cc] = {};
    const float* h = hidden + (long)row * Hc;
    for (int k = lane; k < Hc; k += 64) {
        float hv = h[k];
        #pragma unroll
        for (int c = 0; c < Cc; c++) acc[c] += hv * Wfc[k * Cc + c];
    }
    #pragma unroll
    for (int c = 0; c < Cc; c++)
        for (int off = 32; off > 0; off >>= 1) acc[c] += __shfl_down(acc[c], off, 64);
    if (lane == 0) {
        float m = -1e30f;
        #pragma unroll
        for (int c = 0; c < Cc; c++) { acc[c] += bfc[c]; m = fmaxf(m, acc[c]); }
        float s = 0.f;
        #pragma unroll
        for (int c = 0; c < Cc; c++) s += expf(acc[c] - m);
        float lse = logf(s);
        #pragma unroll
        for (int c = 0; c < Cc; c++) out[(long)row * Cc + c] = acc[c] - m - lse;
    }
}

extern "C" void kernel_launch(void* const* d_in, const int* in_sizes, int n_in,
                              void* d_out, int out_size, void* d_ws, size_t ws_size,
                              hipStream_t stream)
{
    const float* feats   = (const float*)d_in[0];
    const float* Wscalar = (const float*)d_in[1];
    const float* W_rel   = (const float*)d_in[2];
    const float* W_root  = (const float*)d_in[3];
    const float* b_rgcn  = (const float*)d_in[4];
    const float* W_nbr   = (const float*)d_in[5];
    const float* W_self  = (const float*)d_in[6];
    const float* b_gc    = (const float*)d_in[7];
    const float* W_match = (const float*)d_in[8];
    const float* b_match = (const float*)d_in[9];
    const float* W_lin   = (const float*)d_in[10];
    const float* b_lin   = (const float*)d_in[11];
    const float* W_fc    = (const float*)d_in[12];
    const float* b_fc    = (const float*)d_in[13];
    const int*   spk     = (const int*)d_in[14];

    char* wsb = (char*)d_ws;
    // byte layout (113.8 MiB total)
    float* scale  = (float*)wsb;                          // [0, 16 MiB) -> dead after edge_norm
    float* h1     = (float*)wsb;                          // [0, 32 MiB) -> dead after anh1
    float* hidden = (float*)wsb;                          // [0, 32 MiB)
    float* enorm  = (float*)(wsb + 33554432);             // 1.3 MiB
    unsigned short* WT      = (unsigned short*)(wsb + 34930688);  // 17.3 MiB total
    unsigned short* WscalarT = WT;                // 256x1024
    unsigned short* WrelT    = WT + 262144;       // 4096x1024
    unsigned short* WrootT   = WT + 4456448;      // 512x1024
    unsigned short* WgcT     = WT + 4980736;      // 512x1024 (nbr | self)
    unsigned short* WmatchT  = WT + 5505024;      // 1536x1536
    unsigned short* WlinT    = WT + 7864320;      // 512x1536
    unsigned short* hallbf = (unsigned short*)(wsb + 52232192);   // 2048x4096 bf16
    unsigned short* anh1   = (unsigned short*)(wsb + 69009408);   // 16384x1024 bf16 (32 MiB)
    // after anh1 dead: per-chunk attention scratch in same region
    unsigned short* emc  = (unsigned short*)(wsb + 69009408);     // 2048x1536
    unsigned short* xtc  = (unsigned short*)(wsb + 75300864);     // 2048x1536
    float*          Sc   = (float*)(wsb + 81592320);              // 2048x256 f32
    unsigned short* ac   = (unsigned short*)(wsb + 83689472);     // 2048x256
    unsigned short* attc = (unsigned short*)(wsb + 84738048);     // 2048x1536
    unsigned short* h2bf = (unsigned short*)(wsb + 102563840);    // 16384x512 bf16

    // ---- weight transposes (fp32 -> bf16 BT)
    transpose_w<<<dim3(8, 32, 1), 256, 0, stream>>>(Wscalar, WscalarT, 256, 1024, 0, 0);
    transpose_w<<<dim3(16, 32, 8), 256, 0, stream>>>(W_rel, WrelT, 512, 1024, 524288, 524288);
    transpose_w<<<dim3(16, 32, 1), 256, 0, stream>>>(W_root, WrootT, 512, 1024, 0, 0);
    transpose_w<<<dim3(16, 16, 1), 256, 0, stream>>>(W_nbr, WgcT, 512, 1024, 0, 0);
    transpose_w<<<dim3(16, 16, 1), 256, 0, stream>>>(W_self, WgcT + 512, 512, 1024, 0, 0);
    transpose_w<<<dim3(48, 48, 1), 256, 0, stream>>>(W_match, WmatchT, 1536, 1536, 0, 0);
    transpose_w<<<dim3(16, 48, 1), 256, 0, stream>>>(W_lin, WlinT, 512, 1536, 0, 0);

    // ---- 1. scale = feats @ Wscalar   [16384 x 256]
    gemm_mfma<0, 0, false, false, false, false><<<dim3(2, 128, 1), 256, 0, stream>>>(
        feats, WscalarT, scale, nullptr, 1024, 1024, 1024, 256, 0, 0, 0, 0);

    // ---- 2. windowed softmax
    edge_norm_kernel<<<dim3(64), 256, 0, stream>>>(scale, enorm);

    // ---- 3. RGCN per chunk: hall = x @ W_rel (all 8 rels, N=4096), then gather -> h1
    for (int c = 0; c < 8; c++) {
        gemm_mfma<1, 0, true, false, false, false><<<dim3(32, 16, 1), 256, 0, stream>>>(
            feats, WrelT, hallbf, nullptr, 1024, 1024, 1024, 4096, 0, 0, 0, c * 2048);
        rgcn_gather<<<dim3(2048), 256, 0, stream>>>(hallbf, enorm, spk, h1, c * 2048);
    }

    // ---- 4. h1 += x @ W_root + b_rgcn
    gemm_mfma<1, 0, false, true, true, false><<<dim3(4, 128, 1), 256, 0, stream>>>(
        feats, WrootT, h1, b_rgcn, 1024, 1024, 1024, 512, 0, 0, 0, 0);

    // ---- 5. anh1 = concat(nbr-sum(h1), h1); h2 = anh1 @ [W_nbr;W_self] + b_gc
    build_anh1<<<dim3(Nc), 256, 0, stream>>>(h1, anh1);
    gemm_mfma<2, 0, true, false, true, false><<<dim3(4, 128, 1), 256, 0, stream>>>(
        anh1, WgcT, h2bf, b_gc, 1024, 1024, 1024, 512, 0, 0, 0, 0);

    // ---- 6-8. matching attention + classifier head, per 8-conversation chunk
    for (int c = 0; c < 8; c++) {
        int base = c * 2048;
        build_emc<<<dim3(2048), 256, 0, stream>>>(feats, h2bf, emc, base);
        // xt = em @ W_match + b_match
        gemm_mfma<2, 0, true, false, true, false><<<dim3(12, 16, 1), 256, 0, stream>>>(
            emc, WmatchT, xtc, b_match, 1536, 1536, 1536, 1536, 0, 0, 0, 0);
        // S_b = xt_b @ em_b^T   (z = 8 convs)
        gemm_mfma<2, 0, false, false, false, false><<<dim3(2, 2, 8), 256, 0, stream>>>(
            xtc, emc, Sc, nullptr, 1536, 1536, 1536, 256, 393216, 393216, 65536, 0);
        // a = softmax(tanh(S))
        tanh_softmax_rows<<<dim3(2048), 256, 0, stream>>>(Sc, ac);
        // att_b = a_b @ em_b    (B normal orientation)
        gemm_mfma<2, 1, true, false, false, false><<<dim3(12, 2, 8), 256, 0, stream>>>(
            ac, emc, attc, nullptr, 256, 256, 1536, 1536, 65536, 393216, 393216, 0);
        // hidden = relu(att @ W_lin + b_lin)
        gemm_mfma<2, 0, false, false, true, true><<<dim3(4, 16, 1), 256, 0, stream>>>(
            attc, WlinT, hidden + (long)base * Hc, b_lin, 1536, 1536, 1536, 512, 0, 0, 0, 0);
    }

    // ---- 9. logits + log_softmax
    out_kernel<<<dim3(Nc / 4), 256, 0, stream>>>(hidden, W_fc, b_fc, (float*)d_out);
}

// Round 6
// 1485.436 us; speedup vs baseline: 7.4363x; 1.5705x over previous
//
#include <hip/hip_runtime.h>
#include <hip/hip_bf16.h>

// Problem constants
#define Lc 256
#define Bc 64
#define Dc 1024
#define Hc 512
#define Rc 8
#define Cc 6
#define WINc 10
#define NWc 21
#define Nc (Bc*Lc)        // 16384
#define DHc (Dc+Hc)       // 1536

typedef __attribute__((ext_vector_type(8))) short short8;
typedef __attribute__((ext_vector_type(4))) float floatx4;

__device__ inline unsigned short f2b(float x) {
    __hip_bfloat16 h = __float2bfloat16(x);
    return *reinterpret_cast<unsigned short*>(&h);
}
__device__ inline float bf2f(unsigned short u) {
    __hip_bfloat16 h;
    *reinterpret_cast<unsigned short*>(&h) = u;
    return __bfloat162float(h);
}

// node id n = b*256+s  ->  feats row s*64+b
__device__ inline long remap_row(int node) { return (long)(((node & 255) << 6) + (node >> 8)); }

// ---------------- weight transpose fp32 [K][N] -> bf16 [N][K] (ldo) ----------------
__global__ __launch_bounds__(256) void transpose_w(const float* __restrict__ in,
        unsigned short* __restrict__ out, int N, int ldo, long s_in, long s_out)
{
    __shared__ float t[32][33];
    int z = blockIdx.z;
    int n0 = blockIdx.x * 32, k0 = blockIdx.y * 32;
    int tx = threadIdx.x & 31, ty = threadIdx.x >> 5;
    const float* ip = in + z * s_in;
    unsigned short* op = out + z * s_out;
    #pragma unroll
    for (int i = 0; i < 4; i++) t[ty + i * 8][tx] = ip[(long)(k0 + ty + i * 8) * N + n0 + tx];
    __syncthreads();
    #pragma unroll
    for (int i = 0; i < 4; i++) op[(long)(n0 + ty + i * 8) * ldo + k0 + tx] = f2b(t[tx][ty + i * 8]);
}

// ---------------- MFMA GEMM ----------------
// AMODE 0: A fp32 plain rows          AMODE 1: A fp32 rows remap(m+m_off)
// AMODE 2: A bf16 plain rows          AMODE 3: A = em-view (feats fp32 | h2bf bf16), node = m
// BMODE 0: BT bf16 [n][k]             BMODE 1: B bf16 normal [k][n]
// BMODE 2: BT em-view, node = z*256 + n
// CBF: write bf16 else fp32. Tile 128x128, BK=32, 4 waves.
template<int AMODE, int BMODE, bool CBF, bool BIAS, bool RELU>
__global__ __launch_bounds__(256) void gemm_mfma(
    const void* __restrict__ Av, const void* __restrict__ Bv, void* __restrict__ Cv,
    const float* __restrict__ bias,
    const float* __restrict__ feats, const unsigned short* __restrict__ h2buf,
    int K, int lda, int ldb, int ldc,
    long sA, long sB, long sC, int m_off)
{
    __shared__ __align__(16) unsigned short As[128 * 40];
    __shared__ __align__(16) unsigned short Bs[128 * 40];
    const int tid = threadIdx.x;
    const int z = blockIdx.z;
    const int m0 = blockIdx.y * 128;
    const int n0 = blockIdx.x * 128;
    const int lane = tid & 63;
    const int wave = tid >> 6;
    const int wrow = (wave >> 1) * 64;
    const int wcol = (wave & 1) * 64;
    const int q = lane >> 4;
    const int mr = lane & 15;

    floatx4 acc[4][4];
    #pragma unroll
    for (int mt = 0; mt < 4; mt++)
        #pragma unroll
        for (int nt = 0; nt < 4; nt++) acc[mt][nt] = (floatx4){0.f, 0.f, 0.f, 0.f};

    const int r = tid & 127, hh = tid >> 7;        // A / BT staging map
    const int kk = tid >> 3, cg = (tid & 7) * 16;  // B-normal staging map

    long abase;
    if (AMODE == 1)      abase = remap_row(m0 + r + m_off) * (long)lda;
    else if (AMODE == 3) abase = 0;
    else                 abase = (long)(m0 + r) * lda + z * sA;

    for (int k0 = 0; k0 < K; k0 += 32) {
        // ---- stage A tile (128 x 32)
        if (AMODE == 0 || AMODE == 1) {
            const float* ap = (const float*)Av + abase + k0 + hh * 16;
            float4 f0 = ((const float4*)ap)[0];
            float4 f1 = ((const float4*)ap)[1];
            float4 f2 = ((const float4*)ap)[2];
            float4 f3 = ((const float4*)ap)[3];
            __align__(16) unsigned short tmp[16];
            tmp[0]=f2b(f0.x); tmp[1]=f2b(f0.y); tmp[2]=f2b(f0.z); tmp[3]=f2b(f0.w);
            tmp[4]=f2b(f1.x); tmp[5]=f2b(f1.y); tmp[6]=f2b(f1.z); tmp[7]=f2b(f1.w);
            tmp[8]=f2b(f2.x); tmp[9]=f2b(f2.y); tmp[10]=f2b(f2.z); tmp[11]=f2b(f2.w);
            tmp[12]=f2b(f3.x); tmp[13]=f2b(f3.y); tmp[14]=f2b(f3.z); tmp[15]=f2b(f3.w);
            *(short8*)&As[r * 40 + hh * 16]     = *(short8*)&tmp[0];
            *(short8*)&As[r * 40 + hh * 16 + 8] = *(short8*)&tmp[8];
        } else if (AMODE == 2) {
            const unsigned short* ap = (const unsigned short*)Av + (long)(m0 + r) * lda + z * sA + k0 + hh * 16;
            *(short8*)&As[r * 40 + hh * 16]     = ((const short8*)ap)[0];
            *(short8*)&As[r * 40 + hh * 16 + 8] = ((const short8*)ap)[1];
        } else { // em-view
            int node = m0 + r;
            if (k0 < Dc) {
                const float* ap = feats + remap_row(node) * Dc + k0 + hh * 16;
                float4 f0 = ((const float4*)ap)[0];
                float4 f1 = ((const float4*)ap)[1];
                float4 f2 = ((const float4*)ap)[2];
                float4 f3 = ((const float4*)ap)[3];
                __align__(16) unsigned short tmp[16];
                tmp[0]=f2b(f0.x); tmp[1]=f2b(f0.y); tmp[2]=f2b(f0.z); tmp[3]=f2b(f0.w);
                tmp[4]=f2b(f1.x); tmp[5]=f2b(f1.y); tmp[6]=f2b(f1.z); tmp[7]=f2b(f1.w);
                tmp[8]=f2b(f2.x); tmp[9]=f2b(f2.y); tmp[10]=f2b(f2.z); tmp[11]=f2b(f2.w);
                tmp[12]=f2b(f3.x); tmp[13]=f2b(f3.y); tmp[14]=f2b(f3.z); tmp[15]=f2b(f3.w);
                *(short8*)&As[r * 40 + hh * 16]     = *(short8*)&tmp[0];
                *(short8*)&As[r * 40 + hh * 16 + 8] = *(short8*)&tmp[8];
            } else {
                const unsigned short* ap = h2buf + (long)node * Hc + (k0 - Dc) + hh * 16;
                *(short8*)&As[r * 40 + hh * 16]     = ((const short8*)ap)[0];
                *(short8*)&As[r * 40 + hh * 16 + 8] = ((const short8*)ap)[1];
            }
        }
        // ---- stage B tile (32 x 128) as [n][k]
        if (BMODE == 0) {
            const unsigned short* bp = (const unsigned short*)Bv + z * sB + (long)(n0 + r) * ldb + k0 + hh * 16;
            *(short8*)&Bs[r * 40 + hh * 16]     = ((const short8*)bp)[0];
            *(short8*)&Bs[r * 40 + hh * 16 + 8] = ((const short8*)bp)[1];
        } else if (BMODE == 1) {
            const unsigned short* bp = (const unsigned short*)Bv + z * sB + (long)(k0 + kk) * ldb + n0 + cg;
            short8 w0 = ((const short8*)bp)[0];
            short8 w1 = ((const short8*)bp)[1];
            #pragma unroll
            for (int i = 0; i < 8; i++) Bs[(cg + i) * 40 + kk] = (unsigned short)w0[i];
            #pragma unroll
            for (int i = 0; i < 8; i++) Bs[(cg + 8 + i) * 40 + kk] = (unsigned short)w1[i];
        } else { // em-view BT
            int node = z * Lc + n0 + r;
            if (k0 < Dc) {
                const float* bp = feats + remap_row(node) * Dc + k0 + hh * 16;
                float4 f0 = ((const float4*)bp)[0];
                float4 f1 = ((const float4*)bp)[1];
                float4 f2 = ((const float4*)bp)[2];
                float4 f3 = ((const float4*)bp)[3];
                __align__(16) unsigned short tmp[16];
                tmp[0]=f2b(f0.x); tmp[1]=f2b(f0.y); tmp[2]=f2b(f0.z); tmp[3]=f2b(f0.w);
                tmp[4]=f2b(f1.x); tmp[5]=f2b(f1.y); tmp[6]=f2b(f1.z); tmp[7]=f2b(f1.w);
                tmp[8]=f2b(f2.x); tmp[9]=f2b(f2.y); tmp[10]=f2b(f2.z); tmp[11]=f2b(f2.w);
                tmp[12]=f2b(f3.x); tmp[13]=f2b(f3.y); tmp[14]=f2b(f3.z); tmp[15]=f2b(f3.w);
                *(short8*)&Bs[r * 40 + hh * 16]     = *(short8*)&tmp[0];
                *(short8*)&Bs[r * 40 + hh * 16 + 8] = *(short8*)&tmp[8];
            } else {
                const unsigned short* bp = h2buf + (long)node * Hc + (k0 - Dc) + hh * 16;
                *(short8*)&Bs[r * 40 + hh * 16]     = ((const short8*)bp)[0];
                *(short8*)&Bs[r * 40 + hh * 16 + 8] = ((const short8*)bp)[1];
            }
        }
        __syncthreads();
        short8 af[4], bfv[4];
        #pragma unroll
        for (int mt = 0; mt < 4; mt++) af[mt]  = *(const short8*)&As[(wrow + mt * 16 + mr) * 40 + q * 8];
        #pragma unroll
        for (int nt = 0; nt < 4; nt++) bfv[nt] = *(const short8*)&Bs[(wcol + nt * 16 + mr) * 40 + q * 8];
        #pragma unroll
        for (int mt = 0; mt < 4; mt++)
            #pragma unroll
            for (int nt = 0; nt < 4; nt++)
                acc[mt][nt] = __builtin_amdgcn_mfma_f32_16x16x32_bf16(af[mt], bfv[nt], acc[mt][nt], 0, 0, 0);
        __syncthreads();
    }

    float* Cf = (float*)Cv;
    unsigned short* Cb = (unsigned short*)Cv;
    #pragma unroll
    for (int mt = 0; mt < 4; mt++) {
        #pragma unroll
        for (int nt = 0; nt < 4; nt++) {
            int col = n0 + wcol + nt * 16 + mr;
            float bv = BIAS ? bias[col] : 0.f;
            #pragma unroll
            for (int rg = 0; rg < 4; rg++) {
                int row = m0 + wrow + mt * 16 + q * 4 + rg;
                long ci = z * sC + (long)row * ldc + col;
                float v = acc[mt][nt][rg] + bv;
                if (RELU) v = fmaxf(v, 0.f);
                if (CBF) Cb[ci] = f2b(v);
                else     Cf[ci] = v;
            }
        }
    }
}

// ---------------- edge_norm: windowed softmax over k ----------------
__global__ __launch_bounds__(256) void edge_norm_kernel(const float* __restrict__ scale,
                                                        float* __restrict__ enorm)
{
    int g = blockIdx.x * 256 + threadIdx.x;   // b*L + j
    int b = g >> 8, j = g & 255;
    int klo = max(0, j - WINc), khi = min(Lc - 1, j + WINc);
    float vals[NWc];
    float m = -1e30f;
    for (int k = klo; k <= khi; k++) {
        float v = scale[((long)k * Bc + b) * Lc + j];
        vals[k - klo] = v;
        m = fmaxf(m, v);
    }
    float s = 0.f;
    for (int k = klo; k <= khi; k++) {
        float e = expf(vals[k - klo] - m);
        vals[k - klo] = e;
        s += e;
    }
    float inv = 1.f / s;
    for (int k = klo; k <= khi; k++)
        enorm[(long)g * NWc + (k - j + WINc)] = vals[k - klo] * inv;
}

// ---------------- RGCN aggregation + root + bias (hall bf16 [2048][4608]) ----------------
__global__ __launch_bounds__(256) void rgcn_gather(const unsigned short* __restrict__ hall,
        const float* __restrict__ enorm, const int* __restrict__ speakers,
        const float* __restrict__ b_rgcn, float* __restrict__ h1, int chunk_base)
{
    int nloc = blockIdx.x;
    int n = chunk_base + nloc;
    int b = n >> 8, k = n & 255;
    int tid = threadIdx.x;
    int spk = speakers[k * Bc + b];
    int jlo = max(0, k - WINc), jhi = min(Lc - 1, k + WINc);
    const unsigned short* rootp = hall + (long)nloc * (9 * Hc) + 8 * Hc;
    float a0 = bf2f(rootp[tid]) + b_rgcn[tid];
    float a1 = bf2f(rootp[tid + 256]) + b_rgcn[tid + 256];
    for (int j = jlo; j <= jhi; j++) {
        int spj = speakers[j * Bc + b];
        int rel = spj * 4 + spk * 2 + ((j < k) ? 0 : 1);
        float w = enorm[((long)((b << 8) + j)) * NWc + (k - j + WINc)];
        const unsigned short* src = hall + ((long)(nloc - k + j)) * (9 * Hc) + rel * Hc;
        a0 += w * bf2f(src[tid]);
        a1 += w * bf2f(src[tid + 256]);
    }
    h1[(long)n * Hc + tid] = a0;
    h1[(long)n * Hc + tid + 256] = a1;
}

// ---------------- anh1 = bf16[ concat(window-sum(h1), h1) ]  [N][1024] ----------------
__global__ __launch_bounds__(256) void build_anh1(const float* __restrict__ h1,
                                                  unsigned short* __restrict__ anh1)
{
    int n = blockIdx.x;
    int b = n >> 8, k = n & 255;
    int tid = threadIdx.x;
    int jlo = max(0, k - WINc), jhi = min(Lc - 1, k + WINc);
    float a0 = 0.f, a1 = 0.f;
    for (int j = jlo; j <= jhi; j++) {
        const float* src = h1 + ((long)((b << 8) + j)) * Hc;
        a0 += src[tid];
        a1 += src[tid + 256];
    }
    unsigned short* dst = anh1 + (long)n * 1024;
    const float* self = h1 + (long)n * Hc;
    dst[tid]       = f2b(a0);
    dst[tid + 256] = f2b(a1);
    dst[tid + 512] = f2b(self[tid]);
    dst[tid + 768] = f2b(self[tid + 256]);
}

// ---------------- tanh + row softmax -> bf16 attention weights ----------------
__global__ __launch_bounds__(256) void tanh_softmax_rows(const float* __restrict__ S,
                                                         unsigned short* __restrict__ a)
{
    int row = blockIdx.x;
    int tid = threadIdx.x;
    __shared__ float red[256];
    float v = tanhf(S[(long)row * Lc + tid]);
    red[tid] = v; __syncthreads();
    for (int s = 128; s > 0; s >>= 1) { if (tid < s) red[tid] = fmaxf(red[tid], red[tid + s]); __syncthreads(); }
    float m = red[0]; __syncthreads();
    float e = expf(v - m);
    red[tid] = e; __syncthreads();
    for (int s = 128; s > 0; s >>= 1) { if (tid < s) red[tid] += red[tid + s]; __syncthreads(); }
    float sum = red[0];
    a[(long)row * Lc + tid] = f2b(e / sum);
}

// ---------------- final classifier + log_softmax (fp32 out) ----------------
__global__ __launch_bounds__(256) void out_kernel(const float* __restrict__ hidden,
        const float* __restrict__ Wfc, const float* __restrict__ bfc, float* __restrict__ out)
{
    int tid = threadIdx.x;
    int lane = tid & 63;
    int row = blockIdx.x * 4 + (tid >> 6);
    float acc[Cc] = {};
    const float* h = hidden + (long)row * Hc;
    for (int k = lane; k < Hc; k += 64) {
        float hv = h[k];
        #pragma unroll
        for (int c = 0; c < Cc; c++) acc[c] += hv * Wfc[k * Cc + c];
    }
    #pragma unroll
    for (int c = 0; c < Cc; c++)
        for (int off = 32; off > 0; off >>= 1) acc[c] += __shfl_down(acc[c], off, 64);
    if (lane == 0) {
        float m = -1e30f;
        #pragma unroll
        for (int c = 0; c < Cc; c++) { acc[c] += bfc[c]; m = fmaxf(m, acc[c]); }
        float s = 0.f;
        #pragma unroll
        for (int c = 0; c < Cc; c++) s += expf(acc[c] - m);
        float lse = logf(s);
        #pragma unroll
        for (int c = 0; c < Cc; c++) out[(long)row * Cc + c] = acc[c] - m - lse;
    }
}

extern "C" void kernel_launch(void* const* d_in, const int* in_sizes, int n_in,
                              void* d_out, int out_size, void* d_ws, size_t ws_size,
                              hipStream_t stream)
{
    const float* feats   = (const float*)d_in[0];
    const float* Wscalar = (const float*)d_in[1];
    const float* W_rel   = (const float*)d_in[2];
    const float* W_root  = (const float*)d_in[3];
    const float* b_rgcn  = (const float*)d_in[4];
    const float* W_nbr   = (const float*)d_in[5];
    const float* W_self  = (const float*)d_in[6];
    const float* b_gc    = (const float*)d_in[7];
    const float* W_match = (const float*)d_in[8];
    const float* b_match = (const float*)d_in[9];
    const float* W_lin   = (const float*)d_in[10];
    const float* b_lin   = (const float*)d_in[11];
    const float* W_fc    = (const float*)d_in[12];
    const float* b_fc    = (const float*)d_in[13];
    const int*   spk     = (const int*)d_in[14];

    char* wsb = (char*)d_ws;
    // Region plan (148 MB peak):
    float* scale  = (float*)wsb;                          // [0,16MB) -> dead after edge_norm
    float* h1     = (float*)wsb;                          // [0,32MB) -> dead after build_anh1
    float* hidden = (float*)wsb;                          // [0,32MB)
    float* enorm  = (float*)(wsb + 33554432);             // 1.31 MB
    unsigned short* WT = (unsigned short*)(wsb + 34930688);
    unsigned short* WscalarT = WT;                  // 256x1024
    unsigned short* WrelT    = WT + 262144;         // 4608x1024 (8 rels + root)
    unsigned short* WgcT     = WT + 4980736;        // 512x1024 (nbr|self)
    unsigned short* WmatchT  = WT + 5505024;        // 1536x1536
    unsigned short* WlinT    = WT + 7864320;        // 512x1536  (end el 8650752)
    unsigned short* hall = (unsigned short*)(wsb + 52232192);  // 2048x4608 bf16 (18.9MB) -> dead
    unsigned short* h2bf = (unsigned short*)(wsb + 52232192);  // 16384x512 bf16 (16MB), after hall
    unsigned short* anh1 = (unsigned short*)(wsb + 71106560);  // 16384x1024 bf16 (32MB) -> dead
    float*          S    = (float*)(wsb + 71106560);           // 64x256x256 fp32 (16MB), after anh1
    unsigned short* ac   = (unsigned short*)(wsb + 87883776);  // 16384x256 bf16 (8MB)
    unsigned short* xt   = (unsigned short*)(wsb + 104660992); // 16384x1536 bf16 (48MB) -> dead after S
    unsigned short* emW  = (unsigned short*)(wsb + 104660992); // 16384x512 bf16 (16MB), after xt
    // peak = 104660992 + 50331648 = 154,992,640 B ~= 148 MB

    // ---- weight transposes (fp32 -> bf16 BT)
    transpose_w<<<dim3(8, 32, 1), 256, 0, stream>>>(Wscalar, WscalarT, 256, 1024, 0, 0);
    transpose_w<<<dim3(16, 32, 8), 256, 0, stream>>>(W_rel, WrelT, 512, 1024, 524288, 524288);
    transpose_w<<<dim3(16, 32, 1), 256, 0, stream>>>(W_root, WrelT + 4096 * 1024, 512, 1024, 0, 0);
    transpose_w<<<dim3(16, 16, 1), 256, 0, stream>>>(W_nbr, WgcT, 512, 1024, 0, 0);
    transpose_w<<<dim3(16, 16, 1), 256, 0, stream>>>(W_self, WgcT + 512, 512, 1024, 0, 0);
    transpose_w<<<dim3(48, 48, 1), 256, 0, stream>>>(W_match, WmatchT, 1536, 1536, 0, 0);
    transpose_w<<<dim3(16, 48, 1), 256, 0, stream>>>(W_lin, WlinT, 512, 1536, 0, 0);

    // ---- 1. scale = feats @ Wscalar  [16384 x 256] (rows already s*64+b order)
    gemm_mfma<0, 0, false, false, false><<<dim3(2, 128, 1), 256, 0, stream>>>(
        feats, WscalarT, scale, nullptr, feats, nullptr, 1024, 1024, 1024, 256, 0, 0, 0, 0);

    // ---- 2. windowed softmax
    edge_norm_kernel<<<dim3(64), 256, 0, stream>>>(scale, enorm);

    // ---- 3. RGCN per chunk: hall = x @ [W_rel(8) | W_root]  (N=4608), gather (+root+bias) -> h1
    for (int c = 0; c < 8; c++) {
        gemm_mfma<1, 0, true, false, false><<<dim3(36, 16, 1), 256, 0, stream>>>(
            feats, WrelT, hall, nullptr, feats, nullptr, 1024, 1024, 1024, 4608, 0, 0, 0, c * 2048);
        rgcn_gather<<<dim3(2048), 256, 0, stream>>>(hall, enorm, spk, b_rgcn, h1, c * 2048);
    }

    // ---- 4. anh1 = concat(window-sum(h1), h1);  h2 = anh1 @ [W_nbr;W_self] + b_gc
    build_anh1<<<dim3(Nc), 256, 0, stream>>>(h1, anh1);
    gemm_mfma<2, 0, true, true, false><<<dim3(4, 128, 1), 256, 0, stream>>>(
        anh1, WgcT, h2bf, b_gc, feats, nullptr, 1024, 1024, 1024, 512, 0, 0, 0, 0);

    // ---- 5. xt = em @ W_match + b_match   (em = concat-view, never materialized)
    gemm_mfma<3, 0, true, true, false><<<dim3(12, 128, 1), 256, 0, stream>>>(
        nullptr, WmatchT, xt, b_match, feats, h2bf, 1536, 0, 1536, 1536, 0, 0, 0, 0);

    // ---- 6. S_b = xt_b @ em_b^T  (z = 64 convs)
    gemm_mfma<2, 2, false, false, false><<<dim3(2, 2, 64), 256, 0, stream>>>(
        xt, nullptr, S, nullptr, feats, h2bf, 1536, 1536, 0, 256, 393216, 0, 65536, 0);

    // ---- 7. a = softmax(tanh(S))
    tanh_softmax_rows<<<dim3(Nc), 256, 0, stream>>>(S, ac);

    // ---- 8. emW = em @ W_lin + b_lin   (bias valid inside: softmax rows sum to 1)
    gemm_mfma<3, 0, true, true, false><<<dim3(4, 128, 1), 256, 0, stream>>>(
        nullptr, WlinT, emW, b_lin, feats, h2bf, 1536, 0, 1536, 512, 0, 0, 0, 0);

    // ---- 9. hidden = relu(a @ emW)  (z = 64 convs)
    gemm_mfma<2, 1, false, false, true><<<dim3(4, 2, 64), 256, 0, stream>>>(
        ac, emW, hidden, nullptr, feats, nullptr, 256, 256, 512, 512, 65536, 131072, 131072, 0);

    // ---- 10. logits + log_softmax
    out_kernel<<<dim3(Nc / 4), 256, 0, stream>>>(hidden, W_fc, b_fc, (float*)d_out);
}

// Round 7
// 1114.118 us; speedup vs baseline: 9.9147x; 1.3333x over previous
//
#include <hip/hip_runtime.h>
#include <hip/hip_bf16.h>

// Problem constants
#define Lc 256
#define Bc 64
#define Dc 1024
#define Hc 512
#define Rc 8
#define Cc 6
#define WINc 10
#define NWc 21
#define Nc (Bc*Lc)        // 16384
#define DHc (Dc+Hc)       // 1536

typedef __attribute__((ext_vector_type(8))) short short8;
typedef __attribute__((ext_vector_type(4))) float floatx4;

__device__ inline unsigned short f2b(float x) {
    __hip_bfloat16 h = __float2bfloat16(x);
    return *reinterpret_cast<unsigned short*>(&h);
}
__device__ inline float bf2f(unsigned short u) {
    __hip_bfloat16 h;
    *reinterpret_cast<unsigned short*>(&h) = u;
    return __bfloat162float(h);
}

// node id n = b*256+s  ->  feats row s*64+b
__device__ inline long remap_row(int node) { return (long)(((node & 255) << 6) + (node >> 8)); }

typedef __attribute__((address_space(3))) unsigned int lds_u32;
typedef __attribute__((address_space(1))) unsigned int glb_u32;
__device__ inline void glds16(const unsigned short* g, unsigned short* l) {
    __builtin_amdgcn_global_load_lds((const glb_u32*)g, (lds_u32*)l, 16, 0, 0);
}

// ---------------- weight transpose fp32 [K][N] -> bf16 [N][K] (ldo) ----------------
__global__ __launch_bounds__(256) void transpose_w(const float* __restrict__ in,
        unsigned short* __restrict__ out, int N, int ldo, long s_in, long s_out)
{
    __shared__ float t[32][33];
    int z = blockIdx.z;
    int n0 = blockIdx.x * 32, k0 = blockIdx.y * 32;
    int tx = threadIdx.x & 31, ty = threadIdx.x >> 5;
    const float* ip = in + z * s_in;
    unsigned short* op = out + z * s_out;
    #pragma unroll
    for (int i = 0; i < 4; i++) t[ty + i * 8][tx] = ip[(long)(k0 + ty + i * 8) * N + n0 + tx];
    __syncthreads();
    #pragma unroll
    for (int i = 0; i < 4; i++) op[(long)(n0 + ty + i * 8) * ldo + k0 + tx] = f2b(t[tx][ty + i * 8]);
}

// ---------------- em[:, 0:1024) = bf16(features) in node order ----------------
__global__ __launch_bounds__(256) void build_em_x(const float* __restrict__ feats,
                                                  unsigned short* __restrict__ em)
{
    int n = blockIdx.x;
    int tid = threadIdx.x;
    const float* f = feats + remap_row(n) * Dc;
    float4 v = ((const float4*)f)[tid];
    unsigned short* e = em + (long)n * DHc + tid * 4;
    e[0] = f2b(v.x); e[1] = f2b(v.y); e[2] = f2b(v.z); e[3] = f2b(v.w);
}

// ---------------- MFMA GEMM, async staging, fragment-ordered LDS ----------------
// A: bf16 [m][k] rows (lda), BT: bf16 [n][k] rows (ldb). Tile 128x128, BK=32, 4 waves.
// LDS: 8 groups of (16 rows x 4 kchunks x 8 bf16); slot within group = lane -> linear
// ds_read_b128 (zero bank conflicts) and global_load_lds-compatible (lane-ordered).
template<bool CBF, bool CT, bool BIAS, bool RELU>
__global__ __launch_bounds__(256) void gemm_as(
    const unsigned short* __restrict__ A, const unsigned short* __restrict__ B,
    void* __restrict__ Cv, const float* __restrict__ bias,
    int K, int lda, int ldb, int ldc, long sA, long sB, long sC)
{
    __shared__ __align__(16) unsigned short As[4096];
    __shared__ __align__(16) unsigned short Bs[4096];
    const int tid = threadIdx.x;
    const int z = blockIdx.z;
    const int m0 = blockIdx.y * 128, n0 = blockIdx.x * 128;
    const int lane = tid & 63, wave = tid >> 6;
    const int q = lane >> 4, mr = lane & 15;
    const int wrow = (wave >> 1) * 64, wcol = (wave & 1) * 64;

    const unsigned short* Ag0 = A + z * sA + (long)(m0 + wave * 32 + mr) * lda + q * 8;
    const unsigned short* Ag1 = Ag0 + (long)16 * lda;
    const unsigned short* Bg0 = B + z * sB + (long)(n0 + wave * 32 + mr) * ldb + q * 8;
    const unsigned short* Bg1 = Bg0 + (long)16 * ldb;
    unsigned short* Al0 = As + wave * 1024;
    unsigned short* Bl0 = Bs + wave * 1024;

    floatx4 acc[4][4];
    #pragma unroll
    for (int mt = 0; mt < 4; mt++)
        #pragma unroll
        for (int nt = 0; nt < 4; nt++) acc[mt][nt] = (floatx4){0.f, 0.f, 0.f, 0.f};

    const int ga = (wave >> 1) * 2048;   // A fragment group base (shorts)
    const int gb = (wave & 1) * 2048;    // B fragment group base

    for (int k0 = 0; k0 < K; k0 += 32) {
        glds16(Ag0 + k0, Al0);
        glds16(Ag1 + k0, Al0 + 512);
        glds16(Bg0 + k0, Bl0);
        glds16(Bg1 + k0, Bl0 + 512);
        __syncthreads();
        short8 af[4], bfr[4];
        #pragma unroll
        for (int t = 0; t < 4; t++) {
            af[t]  = *(const short8*)&As[ga + t * 512 + lane * 8];
            bfr[t] = *(const short8*)&Bs[gb + t * 512 + lane * 8];
        }
        #pragma unroll
        for (int mt = 0; mt < 4; mt++)
            #pragma unroll
            for (int nt = 0; nt < 4; nt++)
                acc[mt][nt] = __builtin_amdgcn_mfma_f32_16x16x32_bf16(af[mt], bfr[nt], acc[mt][nt], 0, 0, 0);
        __syncthreads();
    }

    float* Cf = (float*)Cv;
    unsigned short* Cb = (unsigned short*)Cv;
    #pragma unroll
    for (int mt = 0; mt < 4; mt++) {
        #pragma unroll
        for (int nt = 0; nt < 4; nt++) {
            int col = n0 + wcol + nt * 16 + mr;
            float bv = BIAS ? bias[col] : 0.f;
            #pragma unroll
            for (int rg = 0; rg < 4; rg++) {
                int row = m0 + wrow + mt * 16 + q * 4 + rg;
                float v = acc[mt][nt][rg] + bv;
                if (RELU) v = fmaxf(v, 0.f);
                if (CT) {
                    Cb[(long)(row >> 8) * 131072 + (long)col * 256 + (row & 255)] = f2b(v);
                } else {
                    long ci = z * sC + (long)row * ldc + col;
                    if (CBF) Cb[ci] = f2b(v);
                    else     Cf[ci] = v;
                }
            }
        }
    }
}

// ---------------- edge_norm: windowed softmax over k (scale node-ordered) ----------------
__global__ __launch_bounds__(256) void edge_norm_kernel(const float* __restrict__ scale,
                                                        float* __restrict__ enorm)
{
    int g = blockIdx.x * 256 + threadIdx.x;   // b*L + j
    int b = g >> 8, j = g & 255;
    int klo = max(0, j - WINc), khi = min(Lc - 1, j + WINc);
    float vals[NWc];
    float m = -1e30f;
    for (int k = klo; k <= khi; k++) {
        float v = scale[(long)((b << 8) + k) * Lc + j];
        vals[k - klo] = v;
        m = fmaxf(m, v);
    }
    float s = 0.f;
    for (int k = klo; k <= khi; k++) {
        float e = expf(vals[k - klo] - m);
        vals[k - klo] = e;
        s += e;
    }
    float inv = 1.f / s;
    for (int k = klo; k <= khi; k++)
        enorm[(long)g * NWc + (k - j + WINc)] = vals[k - klo] * inv;
}

// ---------------- RGCN aggregation + root + bias (hall bf16 [2048][4608]) ----------------
__global__ __launch_bounds__(256) void rgcn_gather(const unsigned short* __restrict__ hall,
        const float* __restrict__ enorm, const int* __restrict__ speakers,
        const float* __restrict__ b_rgcn, float* __restrict__ h1, int chunk_base)
{
    int nloc = blockIdx.x;
    int n = chunk_base + nloc;
    int b = n >> 8, k = n & 255;
    int tid = threadIdx.x;
    int spk = speakers[k * Bc + b];
    int jlo = max(0, k - WINc), jhi = min(Lc - 1, k + WINc);
    const unsigned short* rootp = hall + (long)nloc * (9 * Hc) + 8 * Hc;
    float a0 = bf2f(rootp[tid]) + b_rgcn[tid];
    float a1 = bf2f(rootp[tid + 256]) + b_rgcn[tid + 256];
    for (int j = jlo; j <= jhi; j++) {
        int spj = speakers[j * Bc + b];
        int rel = spj * 4 + spk * 2 + ((j < k) ? 0 : 1);
        float w = enorm[((long)((b << 8) + j)) * NWc + (k - j + WINc)];
        const unsigned short* src = hall + ((long)(nloc - k + j)) * (9 * Hc) + rel * Hc;
        a0 += w * bf2f(src[tid]);
        a1 += w * bf2f(src[tid + 256]);
    }
    h1[(long)n * Hc + tid] = a0;
    h1[(long)n * Hc + tid + 256] = a1;
}

// ---------------- anh1 = bf16[ concat(window-sum(h1), h1) ]  [N][1024] ----------------
__global__ __launch_bounds__(256) void build_anh1(const float* __restrict__ h1,
                                                  unsigned short* __restrict__ anh1)
{
    int n = blockIdx.x;
    int b = n >> 8, k = n & 255;
    int tid = threadIdx.x;
    int jlo = max(0, k - WINc), jhi = min(Lc - 1, k + WINc);
    float a0 = 0.f, a1 = 0.f;
    for (int j = jlo; j <= jhi; j++) {
        const float* src = h1 + ((long)((b << 8) + j)) * Hc;
        a0 += src[tid];
        a1 += src[tid + 256];
    }
    unsigned short* dst = anh1 + (long)n * 1024;
    const float* self = h1 + (long)n * Hc;
    dst[tid]       = f2b(a0);
    dst[tid + 256] = f2b(a1);
    dst[tid + 512] = f2b(self[tid]);
    dst[tid + 768] = f2b(self[tid + 256]);
}

// ---------------- tanh + row softmax -> bf16 attention weights ----------------
__global__ __launch_bounds__(256) void tanh_softmax_rows(const float* __restrict__ S,
                                                         unsigned short* __restrict__ a)
{
    int row = blockIdx.x;
    int tid = threadIdx.x;
    __shared__ float red[256];
    float v = tanhf(S[(long)row * Lc + tid]);
    red[tid] = v; __syncthreads();
    for (int s = 128; s > 0; s >>= 1) { if (tid < s) red[tid] = fmaxf(red[tid], red[tid + s]); __syncthreads(); }
    float m = red[0]; __syncthreads();
    float e = expf(v - m);
    red[tid] = e; __syncthreads();
    for (int s = 128; s > 0; s >>= 1) { if (tid < s) red[tid] += red[tid + s]; __syncthreads(); }
    float sum = red[0];
    a[(long)row * Lc + tid] = f2b(e / sum);
}

// ---------------- final classifier + log_softmax (fp32 out) ----------------
__global__ __launch_bounds__(256) void out_kernel(const unsigned short* __restrict__ hidden,
        const float* __restrict__ Wfc, const float* __restrict__ bfc, float* __restrict__ out)
{
    int tid = threadIdx.x;
    int lane = tid & 63;
    int row = blockIdx.x * 4 + (tid >> 6);
    float acc[Cc] = {};
    const unsigned short* h = hidden + (long)row * Hc;
    for (int k = lane; k < Hc; k += 64) {
        float hv = bf2f(h[k]);
        #pragma unroll
        for (int c = 0; c < Cc; c++) acc[c] += hv * Wfc[k * Cc + c];
    }
    #pragma unroll
    for (int c = 0; c < Cc; c++)
        for (int off = 32; off > 0; off >>= 1) acc[c] += __shfl_down(acc[c], off, 64);
    if (lane == 0) {
        float m = -1e30f;
        #pragma unroll
        for (int c = 0; c < Cc; c++) { acc[c] += bfc[c]; m = fmaxf(m, acc[c]); }
        float s = 0.f;
        #pragma unroll
        for (int c = 0; c < Cc; c++) s += expf(acc[c] - m);
        float lse = logf(s);
        #pragma unroll
        for (int c = 0; c < Cc; c++) out[(long)row * Cc + c] = acc[c] - m - lse;
    }
}

extern "C" void kernel_launch(void* const* d_in, const int* in_sizes, int n_in,
                              void* d_out, int out_size, void* d_ws, size_t ws_size,
                              hipStream_t stream)
{
    const float* feats   = (const float*)d_in[0];
    const float* Wscalar = (const float*)d_in[1];
    const float* W_rel   = (const float*)d_in[2];
    const float* W_root  = (const float*)d_in[3];
    const float* b_rgcn  = (const float*)d_in[4];
    const float* W_nbr   = (const float*)d_in[5];
    const float* W_self  = (const float*)d_in[6];
    const float* b_gc    = (const float*)d_in[7];
    const float* W_match = (const float*)d_in[8];
    const float* b_match = (const float*)d_in[9];
    const float* W_lin   = (const float*)d_in[10];
    const float* b_lin   = (const float*)d_in[11];
    const float* W_fc    = (const float*)d_in[12];
    const float* b_fc    = (const float*)d_in[13];
    const int*   spk     = (const int*)d_in[14];

    char* wsb = (char*)d_ws;
    // Layout (peak 153.0 MB):
    unsigned short* em    = (unsigned short*)wsb;               // [0,48M) node-ordered concat(x,h2)
    float*          scale = (float*)(wsb + 50331648);           // 16M; dead after edge_norm
    unsigned short* hall  = (unsigned short*)(wsb + 50331648);  // 18.9M; dead after RGCN loop
    unsigned short* anh1  = (unsigned short*)(wsb + 50331648);  // 32M; dead after h2 GEMM
    unsigned short* xt    = (unsigned short*)(wsb + 50331648);  // 48M; dead after S GEMM
    unsigned short* ac    = (unsigned short*)(wsb + 50331648);  // 8M (after xt dead)
    unsigned short* hidden= (unsigned short*)(wsb + 58720256);  // 16M
    float*          h1    = (float*)(wsb + 100663296);          // 32M; dead after build_anh1
    float*          S     = (float*)(wsb + 100663296);          // 16M (after h1 dead)
    unsigned short* emWT  = (unsigned short*)(wsb + 117440512); // 16M
    float*          enorm = (float*)(wsb + 134217728);          // 1.4M
    unsigned short* WT    = (unsigned short*)(wsb + 135659520); // 17.3M -> end 152961024
    unsigned short* WscalarT = WT;                 // 256x1024
    unsigned short* WrelT    = WT + 262144;        // 4608x1024 (8 rels + root)
    unsigned short* WgcT     = WT + 4980736;       // 512x1024 (nbr|self)
    unsigned short* WmatchT  = WT + 5505024;       // 1536x1536
    unsigned short* WlinT    = WT + 7864320;       // 512x1536

    // ---- weight transposes (fp32 -> bf16 BT)
    transpose_w<<<dim3(8, 32, 1), 256, 0, stream>>>(Wscalar, WscalarT, 256, 1024, 0, 0);
    transpose_w<<<dim3(16, 32, 8), 256, 0, stream>>>(W_rel, WrelT, 512, 1024, 524288, 524288);
    transpose_w<<<dim3(16, 32, 1), 256, 0, stream>>>(W_root, WrelT + 4096 * 1024, 512, 1024, 0, 0);
    transpose_w<<<dim3(16, 16, 1), 256, 0, stream>>>(W_nbr, WgcT, 512, 1024, 0, 0);
    transpose_w<<<dim3(16, 16, 1), 256, 0, stream>>>(W_self, WgcT + 512, 512, 1024, 0, 0);
    transpose_w<<<dim3(48, 48, 1), 256, 0, stream>>>(W_match, WmatchT, 1536, 1536, 0, 0);
    transpose_w<<<dim3(16, 48, 1), 256, 0, stream>>>(W_lin, WlinT, 512, 1536, 0, 0);

    // ---- 0. em[:, 0:1024) = bf16 features, node order
    build_em_x<<<dim3(Nc), 256, 0, stream>>>(feats, em);

    // ---- 1. scale = x @ Wscalar   [16384 x 256] fp32
    gemm_as<false, false, false, false><<<dim3(2, 128, 1), 256, 0, stream>>>(
        em, WscalarT, scale, nullptr, 1024, DHc, 1024, 256, 0, 0, 0);

    // ---- 2. windowed softmax
    edge_norm_kernel<<<dim3(64), 256, 0, stream>>>(scale, enorm);

    // ---- 3. RGCN per chunk: hall = x @ [W_rel(8)|W_root], gather(+root+bias) -> h1
    for (int c = 0; c < 8; c++) {
        gemm_as<true, false, false, false><<<dim3(36, 16, 1), 256, 0, stream>>>(
            em + (long)c * 2048 * DHc, WrelT, hall, nullptr, 1024, DHc, 1024, 4608, 0, 0, 0);
        rgcn_gather<<<dim3(2048), 256, 0, stream>>>(hall, enorm, spk, b_rgcn, h1, c * 2048);
    }

    // ---- 4. anh1 = concat(window-sum(h1), h1); h2 -> em[:, 1024:1536)
    build_anh1<<<dim3(Nc), 256, 0, stream>>>(h1, anh1);
    gemm_as<true, false, true, false><<<dim3(4, 128, 1), 256, 0, stream>>>(
        anh1, WgcT, em + 1024, b_gc, 1024, 1024, 1024, DHc, 0, 0, 0);

    // ---- 5. xt = em @ W_match + b_match
    gemm_as<true, false, true, false><<<dim3(12, 128, 1), 256, 0, stream>>>(
        em, WmatchT, xt, b_match, DHc, DHc, DHc, DHc, 0, 0, 0);

    // ---- 6. S_b = xt_b @ em_b^T  (z = 64 convs)
    gemm_as<false, false, false, false><<<dim3(2, 2, 64), 256, 0, stream>>>(
        xt, em, S, nullptr, DHc, DHc, DHc, 256, 393216, 393216, 65536);

    // ---- 7. a = softmax(tanh(S))
    tanh_softmax_rows<<<dim3(Nc), 256, 0, stream>>>(S, ac);

    // ---- 8. emWT[conv][h][t] = (em @ W_lin + b_lin)^T per conv
    gemm_as<true, true, true, false><<<dim3(4, 128, 1), 256, 0, stream>>>(
        em, WlinT, emWT, b_lin, DHc, DHc, DHc, 256, 0, 0, 0);

    // ---- 9. hidden = relu(a @ emW)  (z = 64 convs, bf16 out)
    gemm_as<true, false, false, true><<<dim3(4, 2, 64), 256, 0, stream>>>(
        ac, emWT, hidden, nullptr, 256, 256, 256, 512, 65536, 131072, 131072);

    // ---- 10. logits + log_softmax
    out_kernel<<<dim3(Nc / 4), 256, 0, stream>>>(hidden, W_fc, b_fc, (float*)d_out);
}

// Round 8
// 928.824 us; speedup vs baseline: 11.8926x; 1.1995x over previous
//
#include <hip/hip_runtime.h>
#include <hip/hip_bf16.h>

// Problem constants
#define Lc 256
#define Bc 64
#define Dc 1024
#define Hc 512
#define Rc 8
#define Cc 6
#define WINc 10
#define NWc 21
#define Nc (Bc*Lc)        // 16384
#define DHc (Dc+Hc)       // 1536
#define CH 8192           // RGCN chunk (32 conversations)

typedef __attribute__((ext_vector_type(8))) short short8;
typedef __attribute__((ext_vector_type(4))) float floatx4;

__device__ inline unsigned short f2b(float x) {
    __hip_bfloat16 h = __float2bfloat16(x);
    return *reinterpret_cast<unsigned short*>(&h);
}
__device__ inline float bf2f(unsigned short u) {
    __hip_bfloat16 h;
    *reinterpret_cast<unsigned short*>(&h) = u;
    return __bfloat162float(h);
}

// node id n = b*256+s  ->  feats row s*64+b
__device__ inline long remap_row(int node) { return (long)(((node & 255) << 6) + (node >> 8)); }

typedef __attribute__((address_space(3))) unsigned int lds_u32;
typedef __attribute__((address_space(1))) unsigned int glb_u32;
__device__ inline void glds16(const unsigned short* g, unsigned short* l) {
    __builtin_amdgcn_global_load_lds((const glb_u32*)g, (lds_u32*)l, 16, 0, 0);
}

// ---------------- all weight transposes in ONE launch (fp32 [K][N] -> bf16 [N][K]) ----------------
__global__ __launch_bounds__(256) void transpose_all(
    const float* __restrict__ Wscalar, const float* __restrict__ W_rel,
    const float* __restrict__ W_root, const float* __restrict__ W_nbr,
    const float* __restrict__ W_self, const float* __restrict__ W_match,
    const float* __restrict__ W_lin, unsigned short* __restrict__ WT)
{
    int t = blockIdx.x;
    const float* in; unsigned short* out; int N, ldo, n0, k0;
    if (t < 256) {                       // Wscalar [1024][256] -> [256][1024]
        in = Wscalar; out = WT; N = 256; ldo = 1024;
        n0 = (t & 7) * 32; k0 = (t >> 3) * 32;
    } else if (t < 4352) {               // W_rel 8x[1024][512] -> rows r*512..
        int u = t - 256; int r = u >> 9; u &= 511;
        in = W_rel + (long)r * 524288; out = WT + 262144 + (long)r * 524288; N = 512; ldo = 1024;
        n0 = (u & 15) * 32; k0 = (u >> 4) * 32;
    } else if (t < 4864) {               // W_root -> WrelT rows 4096..4608
        int u = t - 4352;
        in = W_root; out = WT + 262144 + 4096 * 1024; N = 512; ldo = 1024;
        n0 = (u & 15) * 32; k0 = (u >> 4) * 32;
    } else if (t < 5120) {               // W_nbr -> WgcT k 0..512
        int u = t - 4864;
        in = W_nbr; out = WT + 4980736; N = 512; ldo = 1024;
        n0 = (u & 15) * 32; k0 = (u >> 4) * 32;
    } else if (t < 5376) {               // W_self -> WgcT k 512..1024
        int u = t - 5120;
        in = W_self; out = WT + 4980736 + 512; N = 512; ldo = 1024;
        n0 = (u & 15) * 32; k0 = (u >> 4) * 32;
    } else if (t < 7680) {               // W_match [1536][1536]
        int u = t - 5376;
        in = W_match; out = WT + 5505024; N = 1536; ldo = 1536;
        n0 = (u % 48) * 32; k0 = (u / 48) * 32;
    } else {                             // W_lin [1536][512]
        int u = t - 7680;
        in = W_lin; out = WT + 7864320; N = 512; ldo = 1536;
        n0 = (u & 15) * 32; k0 = (u >> 4) * 32;
    }
    __shared__ float tt[32][33];
    int tx = threadIdx.x & 31, ty = threadIdx.x >> 5;
    #pragma unroll
    for (int i = 0; i < 4; i++) tt[ty + i * 8][tx] = in[(long)(k0 + ty + i * 8) * N + n0 + tx];
    __syncthreads();
    #pragma unroll
    for (int i = 0; i < 4; i++) out[(long)(n0 + ty + i * 8) * ldo + k0 + tx] = f2b(tt[tx][ty + i * 8]);
}

// ---------------- stable partition of each chunk's nodes by speaker ----------------
__global__ __launch_bounds__(256) void partition_kernel(const int* __restrict__ spk,
        int* __restrict__ idx, int* __restrict__ cnts)
{
    int c = blockIdx.x;
    int tid = threadIdx.x;
    int base = c * CH;
    __shared__ int zs[256];
    int zcount = 0;
    for (int i = 0; i < CH / 256; i++) {
        int n = base + tid * (CH / 256) + i;
        if (spk[(n & 255) * 64 + (n >> 8)] == 0) zcount++;
    }
    zs[tid] = zcount; __syncthreads();
    for (int off = 1; off < 256; off <<= 1) {
        int v = (tid >= off) ? zs[tid - off] : 0;
        __syncthreads();
        zs[tid] += v;
        __syncthreads();
    }
    int Z = zs[255];
    int zpos = zs[tid] - zcount;                 // exclusive zeros before my range
    int opos = tid * (CH / 256) - zpos;          // ones before my range
    for (int i = 0; i < CH / 256; i++) {
        int nl = tid * (CH / 256) + i;
        int n = base + nl;
        if (spk[(n & 255) * 64 + (n >> 8)] == 0) idx[base + (zpos++)] = nl;
        else                                     idx[base + Z + (opos++)] = nl;
    }
    if (tid == 0) cnts[c] = Z;
}

// ---------------- em[:, 0:1024) = bf16(features) in node order ----------------
__global__ __launch_bounds__(256) void build_em_x(const float* __restrict__ feats,
                                                  unsigned short* __restrict__ em)
{
    int n = blockIdx.x;
    int tid = threadIdx.x;
    const float* f = feats + remap_row(n) * Dc;
    float4 v = ((const float4*)f)[tid];
    unsigned short* e = em + (long)n * DHc + tid * 4;
    e[0] = f2b(v.x); e[1] = f2b(v.y); e[2] = f2b(v.z); e[3] = f2b(v.w);
}

// ---------------- MFMA GEMM, async staging, fragment-ordered LDS (round-7 engine) ----------------
template<bool CBF, bool CT, bool BIAS, bool RELU>
__global__ __launch_bounds__(256) void gemm_as(
    const unsigned short* __restrict__ A, const unsigned short* __restrict__ B,
    void* __restrict__ Cv, const float* __restrict__ bias,
    int K, int lda, int ldb, int ldc, long sA, long sB, long sC)
{
    __shared__ __align__(16) unsigned short As[4096];
    __shared__ __align__(16) unsigned short Bs[4096];
    const int tid = threadIdx.x;
    const int z = blockIdx.z;
    const int m0 = blockIdx.y * 128, n0 = blockIdx.x * 128;
    const int lane = tid & 63, wave = tid >> 6;
    const int q = lane >> 4, mr = lane & 15;
    const int wrow = (wave >> 1) * 64, wcol = (wave & 1) * 64;

    const unsigned short* Ag0 = A + z * sA + (long)(m0 + wave * 32 + mr) * lda + q * 8;
    const unsigned short* Ag1 = Ag0 + (long)16 * lda;
    const unsigned short* Bg0 = B + z * sB + (long)(n0 + wave * 32 + mr) * ldb + q * 8;
    const unsigned short* Bg1 = Bg0 + (long)16 * ldb;
    unsigned short* Al0 = As + wave * 1024;
    unsigned short* Bl0 = Bs + wave * 1024;

    floatx4 acc[4][4];
    #pragma unroll
    for (int mt = 0; mt < 4; mt++)
        #pragma unroll
        for (int nt = 0; nt < 4; nt++) acc[mt][nt] = (floatx4){0.f, 0.f, 0.f, 0.f};

    const int ga = (wave >> 1) * 2048;
    const int gb = (wave & 1) * 2048;

    for (int k0 = 0; k0 < K; k0 += 32) {
        glds16(Ag0 + k0, Al0);
        glds16(Ag1 + k0, Al0 + 512);
        glds16(Bg0 + k0, Bl0);
        glds16(Bg1 + k0, Bl0 + 512);
        __syncthreads();
        short8 af[4], bfr[4];
        #pragma unroll
        for (int t = 0; t < 4; t++) {
            af[t]  = *(const short8*)&As[ga + t * 512 + lane * 8];
            bfr[t] = *(const short8*)&Bs[gb + t * 512 + lane * 8];
        }
        #pragma unroll
        for (int mt = 0; mt < 4; mt++)
            #pragma unroll
            for (int nt = 0; nt < 4; nt++)
                acc[mt][nt] = __builtin_amdgcn_mfma_f32_16x16x32_bf16(af[mt], bfr[nt], acc[mt][nt], 0, 0, 0);
        __syncthreads();
    }

    float* Cf = (float*)Cv;
    unsigned short* Cb = (unsigned short*)Cv;
    #pragma unroll
    for (int mt = 0; mt < 4; mt++) {
        #pragma unroll
        for (int nt = 0; nt < 4; nt++) {
            int col = n0 + wcol + nt * 16 + mr;
            float bv = BIAS ? bias[col] : 0.f;
            #pragma unroll
            for (int rg = 0; rg < 4; rg++) {
                int row = m0 + wrow + mt * 16 + q * 4 + rg;
                float v = acc[mt][nt][rg] + bv;
                if (RELU) v = fmaxf(v, 0.f);
                if (CT) {
                    Cb[(long)(row >> 8) * 131072 + (long)col * 256 + (row & 255)] = f2b(v);
                } else {
                    long ci = z * sC + (long)row * ldc + col;
                    if (CBF) Cb[ci] = f2b(v);
                    else     Cf[ci] = v;
                }
            }
        }
    }
}

// ---------------- row-indexed GEMM for speaker-partitioned RGCN (C scatter, ldc 2560) ----------------
// A = em chunk base; rows gathered via idx[off + m]; early-exit on device count.
template<bool SP1>
__global__ __launch_bounds__(256) void gemm_idx(
    const unsigned short* __restrict__ A, const unsigned short* __restrict__ B,
    unsigned short* __restrict__ C, const int* __restrict__ idx,
    const int* __restrict__ cntp)
{
    const int cnt0 = *cntp;
    const int off  = SP1 ? cnt0 : 0;
    const int M    = SP1 ? (CH - cnt0) : cnt0;
    const int m0 = blockIdx.y * 128;
    if (m0 >= M) return;
    const int n0 = blockIdx.x * 128;
    const int tid = threadIdx.x;
    const int lane = tid & 63, wave = tid >> 6;
    const int q = lane >> 4, mr = lane & 15;
    const int wrow = (wave >> 1) * 64, wcol = (wave & 1) * 64;

    int r0 = m0 + wave * 32 + mr;
    int ar0 = idx[off + min(r0, M - 1)];
    int ar1 = idx[off + min(r0 + 16, M - 1)];
    const unsigned short* Ag0 = A + (long)ar0 * DHc + q * 8;
    const unsigned short* Ag1 = A + (long)ar1 * DHc + q * 8;
    const unsigned short* Bg0 = B + (long)(n0 + wave * 32 + mr) * 1024 + q * 8;
    const unsigned short* Bg1 = Bg0 + 16 * 1024;

    __shared__ __align__(16) unsigned short As[4096];
    __shared__ __align__(16) unsigned short Bs[4096];
    unsigned short* Al0 = As + wave * 1024;
    unsigned short* Bl0 = Bs + wave * 1024;

    floatx4 acc[4][4];
    #pragma unroll
    for (int mt = 0; mt < 4; mt++)
        #pragma unroll
        for (int nt = 0; nt < 4; nt++) acc[mt][nt] = (floatx4){0.f, 0.f, 0.f, 0.f};

    const int ga = (wave >> 1) * 2048;
    const int gb = (wave & 1) * 2048;

    for (int k0 = 0; k0 < 1024; k0 += 32) {
        glds16(Ag0 + k0, Al0);
        glds16(Ag1 + k0, Al0 + 512);
        glds16(Bg0 + k0, Bl0);
        glds16(Bg1 + k0, Bl0 + 512);
        __syncthreads();
        short8 af[4], bfr[4];
        #pragma unroll
        for (int t = 0; t < 4; t++) {
            af[t]  = *(const short8*)&As[ga + t * 512 + lane * 8];
            bfr[t] = *(const short8*)&Bs[gb + t * 512 + lane * 8];
        }
        #pragma unroll
        for (int mt = 0; mt < 4; mt++)
            #pragma unroll
            for (int nt = 0; nt < 4; nt++)
                acc[mt][nt] = __builtin_amdgcn_mfma_f32_16x16x32_bf16(af[mt], bfr[nt], acc[mt][nt], 0, 0, 0);
        __syncthreads();
    }

    #pragma unroll
    for (int mt = 0; mt < 4; mt++) {
        #pragma unroll
        for (int nt = 0; nt < 4; nt++) {
            int col = n0 + wcol + nt * 16 + mr;
            #pragma unroll
            for (int rg = 0; rg < 4; rg++) {
                int row = m0 + wrow + mt * 16 + q * 4 + rg;
                int crow = idx[off + min(row, M - 1)];
                C[(long)crow * 2560 + col] = f2b(acc[mt][nt][rg]);
            }
        }
    }
}

// ---------------- edge_norm: windowed softmax over k (scale node-ordered) ----------------
__global__ __launch_bounds__(256) void edge_norm_kernel(const float* __restrict__ scale,
                                                        float* __restrict__ enorm)
{
    int g = blockIdx.x * 256 + threadIdx.x;   // b*L + j
    int b = g >> 8, j = g & 255;
    int klo = max(0, j - WINc), khi = min(Lc - 1, j + WINc);
    float vals[NWc];
    float m = -1e30f;
    for (int k = klo; k <= khi; k++) {
        float v = scale[(long)((b << 8) + k) * Lc + j];
        vals[k - klo] = v;
        m = fmaxf(m, v);
    }
    float s = 0.f;
    for (int k = klo; k <= khi; k++) {
        float e = expf(vals[k - klo] - m);
        vals[k - klo] = e;
        s += e;
    }
    float inv = 1.f / s;
    for (int k = klo; k <= khi; k++)
        enorm[(long)g * NWc + (k - j + WINc)] = vals[k - klo] * inv;
}

// ---------------- RGCN aggregation (hall4 bf16 [CH][2560]: 4 dst-sel blocks + root) ----------------
__global__ __launch_bounds__(256) void rgcn_gather4(const unsigned short* __restrict__ hall4,
        const float* __restrict__ enorm, const int* __restrict__ spk,
        const float* __restrict__ b_rgcn, float* __restrict__ h1, int chunk_base)
{
    int nloc = blockIdx.x;
    int n = chunk_base + nloc;
    int b = n >> 8, k = n & 255;
    int tid = threadIdx.x;
    int spkk = spk[k * 64 + b];
    int jlo = max(0, k - WINc), jhi = min(Lc - 1, k + WINc);
    unsigned int ru = *(const unsigned int*)(hall4 + (long)nloc * 2560 + 2048 + 2 * tid);
    float a0 = bf2f((unsigned short)(ru & 0xffff)) + b_rgcn[2 * tid];
    float a1 = bf2f((unsigned short)(ru >> 16)) + b_rgcn[2 * tid + 1];
    int cb = spkk * 2;
    for (int j = jlo; j <= jhi; j++) {
        int c = cb + ((j < k) ? 0 : 1);
        float w = enorm[((long)((b << 8) + j)) * NWc + (k - j + WINc)];
        unsigned int u = *(const unsigned int*)(hall4 + ((long)(nloc - k + j)) * 2560 + c * 512 + 2 * tid);
        a0 += w * bf2f((unsigned short)(u & 0xffff));
        a1 += w * bf2f((unsigned short)(u >> 16));
    }
    *(float2*)&h1[(long)n * Hc + 2 * tid] = make_float2(a0, a1);
}

// ---------------- anh1 = bf16[ concat(window-sum(h1), h1) ]  [N][1024] ----------------
__global__ __launch_bounds__(256) void build_anh1(const float* __restrict__ h1,
                                                  unsigned short* __restrict__ anh1)
{
    int n = blockIdx.x;
    int b = n >> 8, k = n & 255;
    int tid = threadIdx.x;
    int jlo = max(0, k - WINc), jhi = min(Lc - 1, k + WINc);
    float a0 = 0.f, a1 = 0.f;
    for (int j = jlo; j <= jhi; j++) {
        const float* src = h1 + ((long)((b << 8) + j)) * Hc;
        a0 += src[tid];
        a1 += src[tid + 256];
    }
    unsigned short* dst = anh1 + (long)n * 1024;
    const float* self = h1 + (long)n * Hc;
    dst[tid]       = f2b(a0);
    dst[tid + 256] = f2b(a1);
    dst[tid + 512] = f2b(self[tid]);
    dst[tid + 768] = f2b(self[tid + 256]);
}

// ---------------- tanh + row softmax -> bf16 attention weights ----------------
__global__ __launch_bounds__(256) void tanh_softmax_rows(const float* __restrict__ S,
                                                         unsigned short* __restrict__ a)
{
    int row = blockIdx.x;
    int tid = threadIdx.x;
    __shared__ float red[256];
    float v = tanhf(S[(long)row * Lc + tid]);
    red[tid] = v; __syncthreads();
    for (int s = 128; s > 0; s >>= 1) { if (tid < s) red[tid] = fmaxf(red[tid], red[tid + s]); __syncthreads(); }
    float m = red[0]; __syncthreads();
    float e = expf(v - m);
    red[tid] = e; __syncthreads();
    for (int s = 128; s > 0; s >>= 1) { if (tid < s) red[tid] += red[tid + s]; __syncthreads(); }
    float sum = red[0];
    a[(long)row * Lc + tid] = f2b(e / sum);
}

// ---------------- final classifier + log_softmax (fp32 out) ----------------
__global__ __launch_bounds__(256) void out_kernel(const unsigned short* __restrict__ hidden,
        const float* __restrict__ Wfc, const float* __restrict__ bfc, float* __restrict__ out)
{
    int tid = threadIdx.x;
    int lane = tid & 63;
    int row = blockIdx.x * 4 + (tid >> 6);
    float acc[Cc] = {};
    const unsigned short* h = hidden + (long)row * Hc;
    for (int k = lane; k < Hc; k += 64) {
        float hv = bf2f(h[k]);
        #pragma unroll
        for (int c = 0; c < Cc; c++) acc[c] += hv * Wfc[k * Cc + c];
    }
    #pragma unroll
    for (int c = 0; c < Cc; c++)
        for (int off = 32; off > 0; off >>= 1) acc[c] += __shfl_down(acc[c], off, 64);
    if (lane == 0) {
        float m = -1e30f;
        #pragma unroll
        for (int c = 0; c < Cc; c++) { acc[c] += bfc[c]; m = fmaxf(m, acc[c]); }
        float s = 0.f;
        #pragma unroll
        for (int c = 0; c < Cc; c++) s += expf(acc[c] - m);
        float lse = logf(s);
        #pragma unroll
        for (int c = 0; c < Cc; c++) out[(long)row * Cc + c] = acc[c] - m - lse;
    }
}

extern "C" void kernel_launch(void* const* d_in, const int* in_sizes, int n_in,
                              void* d_out, int out_size, void* d_ws, size_t ws_size,
                              hipStream_t stream)
{
    const float* feats   = (const float*)d_in[0];
    const float* Wscalar = (const float*)d_in[1];
    const float* W_rel   = (const float*)d_in[2];
    const float* W_root  = (const float*)d_in[3];
    const float* b_rgcn  = (const float*)d_in[4];
    const float* W_nbr   = (const float*)d_in[5];
    const float* W_self  = (const float*)d_in[6];
    const float* b_gc    = (const float*)d_in[7];
    const float* W_match = (const float*)d_in[8];
    const float* b_match = (const float*)d_in[9];
    const float* W_lin   = (const float*)d_in[10];
    const float* b_lin   = (const float*)d_in[11];
    const float* W_fc    = (const float*)d_in[12];
    const float* b_fc    = (const float*)d_in[13];
    const int*   spk     = (const int*)d_in[14];

    char* wsb = (char*)d_ws;
    // Layout (peak 152.9 MB, <= round-7's working 153.0):
    unsigned short* em    = (unsigned short*)wsb;               // [0,48M) persistent
    char* RB = wsb + 50331648;                                  // time-multiplexed region (48M)
    float*          scale = (float*)RB;                         // 16M  (steps 1-2)
    unsigned short* hall4 = (unsigned short*)RB;                // 41.9M (RGCN loop)
    unsigned short* anh1  = (unsigned short*)RB;                // 32M  (anh1 -> h2)
    unsigned short* xt    = (unsigned short*)RB;                // 48M  (xt -> S)
    unsigned short* emWT  = (unsigned short*)RB;                // 16M  (after S)
    unsigned short* hidden= (unsigned short*)(RB + 16777216);   // 16M  (after S)
    char* HB = wsb + 100663296;                                 // second region (32M)
    float*          h1    = (float*)HB;                         // 32M (RGCN -> build_anh1)
    float*          S     = (float*)HB;                         // 16M (after h1 dead)
    unsigned short* ac    = (unsigned short*)(HB + 16777216);   // 8M  (softmax -> hidden)
    int* idx              = (int*)(HB + 16777216);              // 64K (early; clobbered later - ok)
    int* cnts             = (int*)(HB + 16777216 + 65536);      // 8B  (early)
    unsigned short* WT    = (unsigned short*)(wsb + 134217728); // 17.3M persistent
    unsigned short* WscalarT = WT;
    unsigned short* WrelT    = WT + 262144;      // 4608x1024: rels 0..7 then root
    unsigned short* WgcT     = WT + 4980736;     // 512x1024 (nbr k0..512 | self k512..1024)
    unsigned short* WmatchT  = WT + 5505024;     // 1536x1536
    unsigned short* WlinT    = WT + 7864320;     // 512x1536
    float*          enorm = (float*)(wsb + 151519232);          // 1.31M

    // ---- 0a. all weight transposes (1 launch)
    transpose_all<<<dim3(8448), 256, 0, stream>>>(Wscalar, W_rel, W_root, W_nbr, W_self,
                                                  W_match, W_lin, WT);
    // ---- 0b. speaker partition per chunk
    partition_kernel<<<dim3(2), 256, 0, stream>>>(spk, idx, cnts);
    // ---- 0c. em[:, 0:1024) = bf16 features, node order
    build_em_x<<<dim3(Nc), 256, 0, stream>>>(feats, em);

    // ---- 1. scale = x @ Wscalar  [16384 x 256]
    gemm_as<false, false, false, false><<<dim3(2, 128, 1), 256, 0, stream>>>(
        em, WscalarT, scale, nullptr, 1024, DHc, 1024, 256, 0, 0, 0);

    // ---- 2. windowed softmax
    edge_norm_kernel<<<dim3(64), 256, 0, stream>>>(scale, enorm);

    // ---- 3. RGCN per 8192-node chunk: speaker-split 4-transform GEMMs + root, then gather
    for (int c = 0; c < 2; c++) {
        const unsigned short* emc = em + (long)c * CH * DHc;
        gemm_idx<false><<<dim3(16, 64, 1), 256, 0, stream>>>(
            emc, WrelT, hall4, idx + c * CH, cnts + c);
        gemm_idx<true><<<dim3(16, 64, 1), 256, 0, stream>>>(
            emc, WrelT + 2048 * 1024, hall4, idx + c * CH, cnts + c);
        gemm_as<true, false, false, false><<<dim3(4, 64, 1), 256, 0, stream>>>(
            emc, WrelT + 4096 * 1024, hall4 + 2048, nullptr, 1024, DHc, 1024, 2560, 0, 0, 0);
        rgcn_gather4<<<dim3(CH), 256, 0, stream>>>(hall4, enorm, spk, b_rgcn, h1, c * CH);
    }

    // ---- 4. anh1 = concat(window-sum(h1), h1); h2 -> em[:, 1024:1536)
    build_anh1<<<dim3(Nc), 256, 0, stream>>>(h1, anh1);
    gemm_as<true, false, true, false><<<dim3(4, 128, 1), 256, 0, stream>>>(
        anh1, WgcT, em + 1024, b_gc, 1024, 1024, 1024, DHc, 0, 0, 0);

    // ---- 5. xt = em @ W_match + b_match
    gemm_as<true, false, true, false><<<dim3(12, 128, 1), 256, 0, stream>>>(
        em, WmatchT, xt, b_match, DHc, DHc, DHc, DHc, 0, 0, 0);

    // ---- 6. S_b = xt_b @ em_b^T  (z = 64 convs)
    gemm_as<false, false, false, false><<<dim3(2, 2, 64), 256, 0, stream>>>(
        xt, em, S, nullptr, DHc, DHc, DHc, 256, 393216, 393216, 65536);

    // ---- 7. a = softmax(tanh(S))
    tanh_softmax_rows<<<dim3(Nc), 256, 0, stream>>>(S, ac);

    // ---- 8. emWT[conv][h][t] = (em @ W_lin + b_lin)^T per conv   (xt dead -> RB free)
    gemm_as<true, true, true, false><<<dim3(4, 128, 1), 256, 0, stream>>>(
        em, WlinT, emWT, b_lin, DHc, DHc, DHc, 256, 0, 0, 0);

    // ---- 9. hidden = relu(a @ emW)  (z = 64 convs, bf16 out)
    gemm_as<true, false, false, true><<<dim3(4, 2, 64), 256, 0, stream>>>(
        ac, emWT, hidden, nullptr, 256, 256, 256, 512, 65536, 131072, 131072);

    // ---- 10. logits + log_softmax
    out_kernel<<<dim3(Nc / 4), 256, 0, stream>>>(hidden, W_fc, b_fc, (float*)d_out);
}